// Round 14
// baseline (615.197 us; speedup 1.0000x reference)
//
#include <hip/hip_runtime.h>
#include <math.h>

#define DEV __device__ __forceinline__

typedef __attribute__((ext_vector_type(8))) short short8;
typedef __attribute__((ext_vector_type(4))) float f32x4;
typedef unsigned short ushort_t;
typedef unsigned int uint_t;

DEV float siluf(float x){ return x / (1.f + __expf(-x)); }
DEV float softplusf(float x){ return (x > 20.f) ? x : log1pf(__expf(x)); }

DEV ushort_t bf16r(float f){
    uint_t u = __float_as_uint(f);
    return (ushort_t)((u + 0x7fffu + ((u >> 16) & 1u)) >> 16);
}
DEV uint_t pack2(float a, float b){
    return (uint_t)bf16r(a) | ((uint_t)bf16r(b) << 16);
}

// ---------- block reduction helpers (wave64) ----------
DEV void blk_sum2(float &a, float &b, float* sm){
    int lane = threadIdx.x & 63, wid = threadIdx.x >> 6, nw = blockDim.x >> 6;
    #pragma unroll
    for (int off = 32; off; off >>= 1){ a += __shfl_down(a, off); b += __shfl_down(b, off); }
    if (lane == 0){ sm[wid] = a; sm[8 + wid] = b; }
    __syncthreads();
    float ra = 0.f, rb = 0.f;
    for (int i = 0; i < nw; i++){ ra += sm[i]; rb += sm[8 + i]; }
    __syncthreads();
    a = ra; b = rb;
}
DEV float blk_sum1(float v, float* sm){
    int lane = threadIdx.x & 63, wid = threadIdx.x >> 6, nw = blockDim.x >> 6;
    #pragma unroll
    for (int off = 32; off; off >>= 1) v += __shfl_down(v, off);
    if (lane == 0) sm[wid] = v;
    __syncthreads();
    float r = 0.f;
    for (int i = 0; i < nw; i++) r += sm[i];
    __syncthreads();
    return r;
}
DEV float blk_max1(float v, float* sm){
    int lane = threadIdx.x & 63, wid = threadIdx.x >> 6, nw = blockDim.x >> 6;
    #pragma unroll
    for (int off = 32; off; off >>= 1) v = fmaxf(v, __shfl_down(v, off));
    if (lane == 0) sm[wid] = v;
    __syncthreads();
    float r = -3.4e38f;
    for (int i = 0; i < nw; i++) r = fmaxf(r, sm[i]);
    __syncthreads();
    return r;
}

// ---------- transpose body ----------
DEV void tr_body(const float* __restrict__ ip, float* __restrict__ op,
                 int R, int C, int c0, int r0){
    __shared__ float tile[32][33];
    int tx = threadIdx.x & 31, ty = threadIdx.x >> 5;
    #pragma unroll
    for (int rr = ty; rr < 32; rr += 8)
        tile[rr][tx] = ip[(size_t)(r0 + rr) * C + c0 + tx];
    __syncthreads();
    #pragma unroll
    for (int rr = ty; rr < 32; rr += 8)
        op[(size_t)(c0 + rr) * R + r0 + tx] = tile[tx][rr];
}

__global__ __launch_bounds__(256) void k_tr(const float* __restrict__ in,
                                            float* __restrict__ out, int R, int C){
    tr_body(in + (size_t)blockIdx.z * R * C, out + (size_t)blockIdx.z * R * C,
            R, C, blockIdx.x * 32, blockIdx.y * 32);
}

// packed: job0 x->xT (512 blks), job1 ao_w (16), job2 so_w (64)
__global__ __launch_bounds__(256) void k_tr_multi(const float* __restrict__ x,
        float* __restrict__ xT, const float* __restrict__ aow, float* __restrict__ owt,
        const float* __restrict__ sow, float* __restrict__ sowt){
    int idx = blockIdx.x;
    if (idx < 512){
        int bx = idx & 7, by = (idx >> 3) & 3, bz = idx >> 5;
        tr_body(x + (size_t)bz * 32768, xT + (size_t)bz * 32768, 128, 256, bx * 32, by * 32);
    } else if (idx < 528){
        int l = idx - 512;
        tr_body(aow, owt, 128, 128, (l & 3) * 32, (l >> 2) * 32);
    } else {
        int l = idx - 528;
        tr_body(sow, sowt, 256, 256, (l & 7) * 32, (l >> 3) * 32);
    }
}

// ---------- K1: pos-embed + gather ----------
__global__ void k_embed(const float* __restrict__ xT, const int* __restrict__ sidx,
                        float* __restrict__ xs){
    int bl = blockIdx.x; int b = bl >> 8; int c = threadIdx.x;
    int p = sidx[bl];
    int hh = p >> 4, ww = p & 15;
    int pos = (c < 64) ? hh : ww;
    int jm = c & 63;
    float om = __expf(-(float)(jm & 31) * 0.28782313662425574f); // ln(10000)/32
    float ang = (float)pos * om;
    float pe = (jm < 32) ? sinf(ang) : cosf(ang);
    xs[(size_t)bl * 128 + c] = xT[((size_t)(b * 256 + p)) * 128 + c] + pe;
}

// ---------- LayerNorm (block per row) ----------
__global__ void k_ln(const float* __restrict__ in, const float* __restrict__ w,
                     const float* __restrict__ bb, float* __restrict__ out, int dim){
    __shared__ float sm[16];
    int row = blockIdx.x, t = threadIdx.x;
    float v = in[(size_t)row * dim + t];
    float a = v, q = v * v;
    blk_sum2(a, q, sm);
    float inv = 1.f / (float)dim;
    float mu = a * inv;
    float var = q * inv - mu * mu;
    float rs = rsqrtf(var + 1e-5f);
    out[(size_t)row * dim + t] = (v - mu) * rs * w[t] + bb[t];
}

// ======================================================================
// bf16 MFMA GEMM family: 64x64 tile, 256 thr = 4 waves.
// A/B frag: elem [lane&15][quad*8+j]; C/D: col=lane&15, row=quad*4+reg.
// ======================================================================

// ---------- in-projection GEMM with fused LayerNorm (bf16 MFMA) ----------
__global__ __launch_bounds__(256) void k_gemm_ln(const float* __restrict__ A,
        const float* __restrict__ W, const float* __restrict__ lw,
        const float* __restrict__ lb, float* __restrict__ out, int N, int K){
    __shared__ __align__(16) ushort_t smem[2 * 64 * 72];
    ushort_t (*Abf)[72] = (ushort_t (*)[72])smem;
    ushort_t (*Wbf)[72] = (ushort_t (*)[72])(smem + 64 * 72);
    int j0 = blockIdx.x * 64, r0 = blockIdx.y * 64;
    int tid = threadIdx.x;
    int row = tid >> 2, kg = tid & 3;
    int wrow = j0 + row; if (wrow > N - 1) wrow = N - 1;
    const float* Ar = A + (size_t)(r0 + row) * K;
    const float* Wr = W + (size_t)wrow * K;
    float s = 0.f, ss = 0.f;
    for (int k0 = 0; k0 < K; k0 += 32){
        float4 a0 = *(const float4*)(Ar + k0 + kg * 4);
        float4 a1 = *(const float4*)(Ar + k0 + 16 + kg * 4);
        s  += a0.x + a0.y + a0.z + a0.w + a1.x + a1.y + a1.z + a1.w;
        ss += a0.x*a0.x + a0.y*a0.y + a0.z*a0.z + a0.w*a0.w
            + a1.x*a1.x + a1.y*a1.y + a1.z*a1.z + a1.w*a1.w;
    }
    s  += __shfl_xor(s, 1);  ss += __shfl_xor(ss, 1);
    s  += __shfl_xor(s, 2);  ss += __shfl_xor(ss, 2);
    float inv = 1.f / (float)K;
    float mu = s * inv;
    float rs = rsqrtf(ss * inv - mu * mu + 1e-5f);
    int wv = tid >> 6, lane = tid & 63, lm = lane & 15, quad = lane >> 4;
    f32x4 zero4 = {0.f, 0.f, 0.f, 0.f};
    f32x4 acc[4] = {zero4, zero4, zero4, zero4};
    for (int kc0 = 0; kc0 < K; kc0 += 64){
        int kb = kc0 + kg * 16;
        float4 q[4], g[4], b[4], p[4];
        #pragma unroll
        for (int i = 0; i < 4; i++){
            q[i] = *(const float4*)(Ar + kb + i * 4);
            g[i] = *(const float4*)(lw + kb + i * 4);
            b[i] = *(const float4*)(lb + kb + i * 4);
            p[i] = *(const float4*)(Wr + kb + i * 4);
        }
        #pragma unroll
        for (int i = 0; i < 4; i++){
            q[i].x = (q[i].x - mu) * rs * g[i].x + b[i].x;
            q[i].y = (q[i].y - mu) * rs * g[i].y + b[i].y;
            q[i].z = (q[i].z - mu) * rs * g[i].z + b[i].z;
            q[i].w = (q[i].w - mu) * rs * g[i].w + b[i].w;
        }
        __syncthreads();
        {
            uint4 u0, u1;
            u0.x = pack2(q[0].x, q[0].y); u0.y = pack2(q[0].z, q[0].w);
            u0.z = pack2(q[1].x, q[1].y); u0.w = pack2(q[1].z, q[1].w);
            u1.x = pack2(q[2].x, q[2].y); u1.y = pack2(q[2].z, q[2].w);
            u1.z = pack2(q[3].x, q[3].y); u1.w = pack2(q[3].z, q[3].w);
            *(uint4*)&Abf[row][kg * 16] = u0;
            *(uint4*)&Abf[row][kg * 16 + 8] = u1;
            u0.x = pack2(p[0].x, p[0].y); u0.y = pack2(p[0].z, p[0].w);
            u0.z = pack2(p[1].x, p[1].y); u0.w = pack2(p[1].z, p[1].w);
            u1.x = pack2(p[2].x, p[2].y); u1.y = pack2(p[2].z, p[2].w);
            u1.z = pack2(p[3].x, p[3].y); u1.w = pack2(p[3].z, p[3].w);
            *(uint4*)&Wbf[row][kg * 16] = u0;
            *(uint4*)&Wbf[row][kg * 16 + 8] = u1;
        }
        __syncthreads();
        #pragma unroll
        for (int kk = 0; kk < 64; kk += 32){
            short8 af = *(const short8*)&Abf[wv * 16 + lm][kk + quad * 8];
            #pragma unroll
            for (int c = 0; c < 4; c++){
                short8 bfv = *(const short8*)&Wbf[c * 16 + lm][kk + quad * 8];
                acc[c] = __builtin_amdgcn_mfma_f32_16x16x32_bf16(af, bfv, acc[c], 0, 0, 0);
            }
        }
    }
    int rbase = r0 + wv * 16 + quad * 4;
    #pragma unroll
    for (int c = 0; c < 4; c++){
        int j = j0 + c * 16 + lm;
        if (j < N){
            #pragma unroll
            for (int reg = 0; reg < 4; reg++)
                out[(size_t)(rbase + reg) * N + j] = acc[c][reg];
        }
    }
}

// ---------- out-projection GEMM, fused gate(silu)+RMS (bf16 MFMA) ----------
// mode 1: out[r*N+j] = .*scale + res
// mode 2: transposed scatter (N==256): out[((r0>>7)*256+j)*128+(r&127)] = . + res
// mode 4: mode 1 + ALSO write out2 (h1t) transposed: out2[(b*128+j)*256+l] = same value
__global__ __launch_bounds__(256) void k_gemm_gate(const float* __restrict__ Y,
        const float* __restrict__ Z, const float* __restrict__ rw,
        const float* __restrict__ W, const float* __restrict__ res,
        float* __restrict__ out, float* __restrict__ out2,
        int N, int K, int zs, int mode){
    __shared__ __align__(16) ushort_t smem[2 * 64 * 72];
    ushort_t (*Abf)[72] = (ushort_t (*)[72])smem;
    ushort_t (*Wbf)[72] = (ushort_t (*)[72])(smem + 64 * 72);
    __shared__ float sscale[64];
    int j0 = blockIdx.x * 64, r0 = blockIdx.y * 64;
    int tid = threadIdx.x;
    int row = tid >> 2, kg = tid & 3;
    const float* Yr = Y + (size_t)(r0 + row) * K;
    const float* Zr = Z + (size_t)(r0 + row) * zs;
    const float* Wr = W + (size_t)(j0 + row) * K;
    int wv = tid >> 6, lane = tid & 63, lm = lane & 15, quad = lane >> 4;
    float ssq = 0.f;
    f32x4 zero4 = {0.f, 0.f, 0.f, 0.f};
    f32x4 acc[4] = {zero4, zero4, zero4, zero4};
    for (int kc0 = 0; kc0 < K; kc0 += 64){
        int kb = kc0 + kg * 16;
        float4 y[4], z[4], g[4], p[4];
        #pragma unroll
        for (int i = 0; i < 4; i++){
            y[i] = *(const float4*)(Yr + kb + i * 4);
            z[i] = *(const float4*)(Zr + kb + i * 4);
            g[i] = *(const float4*)(rw + kb + i * 4);
            p[i] = *(const float4*)(Wr + kb + i * 4);
        }
        #pragma unroll
        for (int i = 0; i < 4; i++){
            y[i].x *= siluf(z[i].x); y[i].y *= siluf(z[i].y);
            y[i].z *= siluf(z[i].z); y[i].w *= siluf(z[i].w);
            ssq += y[i].x*y[i].x + y[i].y*y[i].y + y[i].z*y[i].z + y[i].w*y[i].w;
            y[i].x *= g[i].x; y[i].y *= g[i].y; y[i].z *= g[i].z; y[i].w *= g[i].w;
        }
        __syncthreads();
        {
            uint4 u0, u1;
            u0.x = pack2(y[0].x, y[0].y); u0.y = pack2(y[0].z, y[0].w);
            u0.z = pack2(y[1].x, y[1].y); u0.w = pack2(y[1].z, y[1].w);
            u1.x = pack2(y[2].x, y[2].y); u1.y = pack2(y[2].z, y[2].w);
            u1.z = pack2(y[3].x, y[3].y); u1.w = pack2(y[3].z, y[3].w);
            *(uint4*)&Abf[row][kg * 16] = u0;
            *(uint4*)&Abf[row][kg * 16 + 8] = u1;
            u0.x = pack2(p[0].x, p[0].y); u0.y = pack2(p[0].z, p[0].w);
            u0.z = pack2(p[1].x, p[1].y); u0.w = pack2(p[1].z, p[1].w);
            u1.x = pack2(p[2].x, p[2].y); u1.y = pack2(p[2].z, p[2].w);
            u1.z = pack2(p[3].x, p[3].y); u1.w = pack2(p[3].z, p[3].w);
            *(uint4*)&Wbf[row][kg * 16] = u0;
            *(uint4*)&Wbf[row][kg * 16 + 8] = u1;
        }
        __syncthreads();
        #pragma unroll
        for (int kk = 0; kk < 64; kk += 32){
            short8 af = *(const short8*)&Abf[wv * 16 + lm][kk + quad * 8];
            #pragma unroll
            for (int c = 0; c < 4; c++){
                short8 bfv = *(const short8*)&Wbf[c * 16 + lm][kk + quad * 8];
                acc[c] = __builtin_amdgcn_mfma_f32_16x16x32_bf16(af, bfv, acc[c], 0, 0, 0);
            }
        }
    }
    ssq += __shfl_xor(ssq, 1);
    ssq += __shfl_xor(ssq, 2);
    if (kg == 0) sscale[row] = rsqrtf(ssq / (float)K + 1e-5f);
    __syncthreads(); // sscale visible; all LDS fragment reads done
    int lr0 = wv * 16 + quad * 4;
    float scr[4];
    #pragma unroll
    for (int reg = 0; reg < 4; reg++) scr[reg] = sscale[lr0 + reg];
    if (mode == 2){
        float (*T)[68] = (float (*)[68])smem;
        #pragma unroll
        for (int c = 0; c < 4; c++)
            #pragma unroll
            for (int reg = 0; reg < 4; reg++)
                T[c * 16 + lm][lr0 + reg] = acc[c][reg] * scr[reg];
        __syncthreads();
        int b2 = r0 >> 7, ii0 = r0 & 127;
        int jj = tid >> 2, seg = tid & 3;
        size_t base = ((size_t)(b2 * 256 + j0 + jj)) * 128 + ii0 + seg * 16;
        float* op = out + base;
        const float* rp = res + base;
        #pragma unroll
        for (int c = 0; c < 4; c++){
            float4 v = *(const float4*)(&T[jj][seg * 16 + c * 4]);
            float4 rv = *(const float4*)(rp + c * 4);
            v.x += rv.x; v.y += rv.y; v.z += rv.z; v.w += rv.w;
            *(float4*)(op + c * 4) = v;
        }
    } else { // mode 1 or 4
        float (*T)[68] = (float (*)[68])smem;
        int rbase = r0 + lr0;
        #pragma unroll
        for (int c = 0; c < 4; c++){
            int j = j0 + c * 16 + lm;
            #pragma unroll
            for (int reg = 0; reg < 4; reg++){
                size_t oi = (size_t)(rbase + reg) * N + j;
                float v = acc[c][reg] * scr[reg] + res[oi];
                out[oi] = v;
                if (mode == 4) T[c * 16 + lm][lr0 + reg] = v;
            }
        }
        if (mode == 4){
            __syncthreads();
            int bb = r0 >> 8, lbase = r0 & 255;
            int jj = tid >> 2, seg = tid & 3;
            size_t base2 = ((size_t)(bb * 128 + j0 + jj)) * 256 + lbase + seg * 16;
            float* op = out2 + base2;
            #pragma unroll
            for (int cc = 0; cc < 4; cc++){
                float4 v = *(const float4*)(&T[jj][seg * 16 + cc * 4]);
                *(float4*)(op + cc * 4) = v;
            }
        }
    }
}

// ---------- qkv GEMM (bf16 MFMA), mode 0: +bias; mode 3: transposed+bias ----------
struct GJob { const float* W; const float* bias; float* out; int mode; };

__global__ __launch_bounds__(256) void k_gemm3(const float* __restrict__ A,
                                               GJob ja, GJob jb, GJob jc,
                                               int N, int K){
    GJob job = (blockIdx.z == 0) ? ja : ((blockIdx.z == 1) ? jb : jc);
    const float* W = job.W;
    const float* bias = job.bias;
    float* out = job.out;
    int mode = job.mode;
    __shared__ __align__(16) ushort_t smem[2 * 64 * 72];
    ushort_t (*Abf)[72] = (ushort_t (*)[72])smem;
    ushort_t (*Wbf)[72] = (ushort_t (*)[72])(smem + 64 * 72);
    int j0 = blockIdx.x * 64, r0 = blockIdx.y * 64;
    int tid = threadIdx.x;
    int row = tid >> 2, kg = tid & 3;
    const float* Ar = A + (size_t)(r0 + row) * K;
    const float* Wr = W + (size_t)(j0 + row) * K;
    int wv = tid >> 6, lane = tid & 63, lm = lane & 15, quad = lane >> 4;
    f32x4 zero4 = {0.f, 0.f, 0.f, 0.f};
    f32x4 acc[4] = {zero4, zero4, zero4, zero4};
    for (int kc0 = 0; kc0 < K; kc0 += 64){
        int kb = kc0 + kg * 16;
        float4 q[4], p[4];
        #pragma unroll
        for (int i = 0; i < 4; i++){
            q[i] = *(const float4*)(Ar + kb + i * 4);
            p[i] = *(const float4*)(Wr + kb + i * 4);
        }
        __syncthreads();
        {
            uint4 u0, u1;
            u0.x = pack2(q[0].x, q[0].y); u0.y = pack2(q[0].z, q[0].w);
            u0.z = pack2(q[1].x, q[1].y); u0.w = pack2(q[1].z, q[1].w);
            u1.x = pack2(q[2].x, q[2].y); u1.y = pack2(q[2].z, q[2].w);
            u1.z = pack2(q[3].x, q[3].y); u1.w = pack2(q[3].z, q[3].w);
            *(uint4*)&Abf[row][kg * 16] = u0;
            *(uint4*)&Abf[row][kg * 16 + 8] = u1;
            u0.x = pack2(p[0].x, p[0].y); u0.y = pack2(p[0].z, p[0].w);
            u0.z = pack2(p[1].x, p[1].y); u0.w = pack2(p[1].z, p[1].w);
            u1.x = pack2(p[2].x, p[2].y); u1.y = pack2(p[2].z, p[2].w);
            u1.z = pack2(p[3].x, p[3].y); u1.w = pack2(p[3].z, p[3].w);
            *(uint4*)&Wbf[row][kg * 16] = u0;
            *(uint4*)&Wbf[row][kg * 16 + 8] = u1;
        }
        __syncthreads();
        #pragma unroll
        for (int kk = 0; kk < 64; kk += 32){
            short8 af = *(const short8*)&Abf[wv * 16 + lm][kk + quad * 8];
            #pragma unroll
            for (int c = 0; c < 4; c++){
                short8 bfv = *(const short8*)&Wbf[c * 16 + lm][kk + quad * 8];
                acc[c] = __builtin_amdgcn_mfma_f32_16x16x32_bf16(af, bfv, acc[c], 0, 0, 0);
            }
        }
    }
    int lr0 = wv * 16 + quad * 4;
    if (mode == 3){
        __syncthreads();
        float (*T)[68] = (float (*)[68])smem;
        #pragma unroll
        for (int c = 0; c < 4; c++)
            #pragma unroll
            for (int reg = 0; reg < 4; reg++)
                T[c * 16 + lm][lr0 + reg] = acc[c][reg];
        __syncthreads();
        int b2 = r0 >> 7, ii0 = r0 & 127;
        int jj = tid >> 2, seg = tid & 3;
        size_t base = ((size_t)(b2 * 256 + j0 + jj)) * 128 + ii0 + seg * 16;
        float* op = out + base;
        float bj = bias[j0 + jj];
        #pragma unroll
        for (int c = 0; c < 4; c++){
            float4 v = *(const float4*)(&T[jj][seg * 16 + c * 4]);
            v.x += bj; v.y += bj; v.z += bj; v.w += bj;
            *(float4*)(op + c * 4) = v;
        }
    } else {
        int rbase = r0 + lr0;
        #pragma unroll
        for (int c = 0; c < 4; c++){
            int j = j0 + c * 16 + lm;
            float bj = bias[j];
            #pragma unroll
            for (int reg = 0; reg < 4; reg++)
                out[(size_t)(rbase + reg) * N + j] = acc[c][reg] + bj;
        }
    }
}

// ---------- chunked SSD, stage A: fused causal conv(4)+silu + dt/log-dA ----------
// Stages X/B/C tiles by computing conv directly from zx (bit-identical to the
// old k_conv + read of xc). dt/dlA computed inline for the 64 chunk rows.
__global__ __launch_bounds__(256) void k_ssd_chunk(
        const float* __restrict__ zx, const float* __restrict__ cw,
        const float* __restrict__ cb, const float* __restrict__ dtbias,
        const float* __restrict__ Al, float* __restrict__ y,
        float* __restrict__ S, float* __restrict__ clb,
        int L, int nh, int nc, int zxs, int zoff, int bo, int co,
        int dtcol, int ys){
    __shared__ float sX[64][68];
    __shared__ float sB[64][68];
    __shared__ float sC[64][68]; // phase1: C ; after: masked G
    __shared__ float cl[64], sdt[64], sw[64];
    int blk = blockIdx.x;
    int c = blk % nc; int bh = blk / nc; int h = bh % nh; int b = bh / nh;
    int l0 = c * 64;
    int tid = threadIdx.x;
    const float* zb = zx + (size_t)(b * L) * zxs + zoff;
    for (int idx = tid; idx < 4096; idx += 256){
        int s = idx >> 6, n = idx & 63;
        int l = l0 + s;
        int d0 = h * 64 + n, d1 = bo + n, d2 = co + n;
        float a0 = cb[d0], a1 = cb[d1], a2 = cb[d2];
        float4 w0 = *(const float4*)(cw + d0 * 4);
        float4 w1 = *(const float4*)(cw + d1 * 4);
        float4 w2 = *(const float4*)(cw + d2 * 4);
        #pragma unroll
        for (int k = 0; k < 4; k++){
            int dl = l + k - 3;
            if (dl >= 0){
                const float* zr = zb + (size_t)dl * zxs;
                a0 += zr[d0] * (&w0.x)[k];
                a1 += zr[d1] * (&w1.x)[k];
                a2 += zr[d2] * (&w2.x)[k];
            }
        }
        sX[s][n] = siluf(a0);
        sB[s][n] = siluf(a1);
        sC[s][n] = siluf(a2);
    }
    if (tid < 64){
        int l = l0 + tid;
        float xv = zx[((size_t)(b * L + l)) * zxs + dtcol + h] + dtbias[h];
        float dtv = softplusf(xv);
        float dlv = -dtv * __expf(Al[h]); // log(dA) <= 0
        sdt[tid] = dtv;
        #pragma unroll
        for (int off = 1; off < 64; off <<= 1){
            float o = __shfl_up(dlv, off, 64);
            if (tid >= off) dlv += o;
        }
        cl[tid] = dlv;
        clb[(size_t)blk * 64 + tid] = dlv;
    }
    __syncthreads();
    if (tid < 64) sw[tid] = __expf(cl[63] - cl[tid]) * sdt[tid];

    int g1 = tid >> 4, g2 = tid & 15;
    int t0 = g1 * 4, s0 = g2 * 4;
    float g[4][4] = {};
    for (int n = 0; n < 64; n += 4){
        float4 cv[4], bv[4];
        #pragma unroll
        for (int i = 0; i < 4; i++) cv[i] = *(const float4*)&sC[t0 + i][n];
        #pragma unroll
        for (int j = 0; j < 4; j++) bv[j] = *(const float4*)&sB[s0 + j][n];
        #pragma unroll
        for (int i = 0; i < 4; i++)
            #pragma unroll
            for (int j = 0; j < 4; j++){
                g[i][j] = fmaf(cv[i].x, bv[j].x, g[i][j]);
                g[i][j] = fmaf(cv[i].y, bv[j].y, g[i][j]);
                g[i][j] = fmaf(cv[i].z, bv[j].z, g[i][j]);
                g[i][j] = fmaf(cv[i].w, bv[j].w, g[i][j]);
            }
    }
    __syncthreads();
    #pragma unroll
    for (int i = 0; i < 4; i++)
        #pragma unroll
        for (int j = 0; j < 4; j++){
            int t = t0 + i, s = s0 + j;
            float v = 0.f;
            if (s <= t) v = g[i][j] * __expf(cl[t] - cl[s]) * sdt[s];
            sC[t][s] = v;
        }
    __syncthreads();
    {
        float acc[4][4] = {};
        for (int s = 0; s < 64; s++){
            float4 xv = *(const float4*)&sX[s][s0];
            float gv[4];
            #pragma unroll
            for (int i = 0; i < 4; i++) gv[i] = sC[t0 + i][s];
            #pragma unroll
            for (int i = 0; i < 4; i++){
                acc[i][0] = fmaf(gv[i], xv.x, acc[i][0]);
                acc[i][1] = fmaf(gv[i], xv.y, acc[i][1]);
                acc[i][2] = fmaf(gv[i], xv.z, acc[i][2]);
                acc[i][3] = fmaf(gv[i], xv.w, acc[i][3]);
            }
        }
        #pragma unroll
        for (int i = 0; i < 4; i++){
            float4 o = make_float4(acc[i][0], acc[i][1], acc[i][2], acc[i][3]);
            *(float4*)&y[(size_t)(b * L + l0 + t0 + i) * ys + h * 64 + s0] = o;
        }
    }
    {
        float acc[4][4] = {};
        int p0 = t0, n0 = s0;
        for (int s = 0; s < 64; s++){
            float wv = sw[s];
            float4 bv = *(const float4*)&sB[s][n0];
            float4 xv = *(const float4*)&sX[s][p0];
            float w0 = wv * xv.x, w1 = wv * xv.y, w2 = wv * xv.z, w3 = wv * xv.w;
            acc[0][0] = fmaf(w0, bv.x, acc[0][0]); acc[0][1] = fmaf(w0, bv.y, acc[0][1]);
            acc[0][2] = fmaf(w0, bv.z, acc[0][2]); acc[0][3] = fmaf(w0, bv.w, acc[0][3]);
            acc[1][0] = fmaf(w1, bv.x, acc[1][0]); acc[1][1] = fmaf(w1, bv.y, acc[1][1]);
            acc[1][2] = fmaf(w1, bv.z, acc[1][2]); acc[1][3] = fmaf(w1, bv.w, acc[1][3]);
            acc[2][0] = fmaf(w2, bv.x, acc[2][0]); acc[2][1] = fmaf(w2, bv.y, acc[2][1]);
            acc[2][2] = fmaf(w2, bv.z, acc[2][2]); acc[2][3] = fmaf(w2, bv.w, acc[2][3]);
            acc[3][0] = fmaf(w3, bv.x, acc[3][0]); acc[3][1] = fmaf(w3, bv.y, acc[3][1]);
            acc[3][2] = fmaf(w3, bv.z, acc[3][2]); acc[3][3] = fmaf(w3, bv.w, acc[3][3]);
        }
        float* Sp = S + (size_t)blk * 4096;
        #pragma unroll
        for (int i = 0; i < 4; i++){
            float4 o = make_float4(acc[i][0], acc[i][1], acc[i][2], acc[i][3]);
            *(float4*)&Sp[(p0 + i) * 64 + n0] = o;
        }
    }
}

// ---------- chunked SSD, stage B+C fused (conv computed inline for C,X tiles) ----------
__global__ __launch_bounds__(256) void k_chunk_y(
        const float* __restrict__ zx, const float* __restrict__ cw,
        const float* __restrict__ cb, const float* __restrict__ S,
        const float* __restrict__ clb, const float* __restrict__ Dp,
        float* __restrict__ y,
        int L, int nh, int nc, int zxs, int zoff, int co, int ys){
    __shared__ float sH[64][68];
    __shared__ float sC[64][68];
    __shared__ float sXc[64][68];
    __shared__ float scl[64];
    int blk = blockIdx.x;
    int c = blk % nc; int bh = blk / nc; int h = bh % nh; int b = bh / nh;
    int l0 = c * 64;
    int tid = threadIdx.x;
    float wch[4];
    {
        float w = 1.f;
        for (int cp = c - 1; cp >= 0; cp--){
            wch[cp] = w;
            w *= __expf(clb[((size_t)(bh * nc + cp)) * 64 + 63]);
        }
    }
    const float* Sb = S + (size_t)(bh * nc) * 4096;
    const float* zb = zx + (size_t)(b * L) * zxs + zoff;
    for (int idx = tid; idx < 4096; idx += 256){
        int r = idx >> 6, n = idx & 63;
        int l = l0 + r;
        float hv = 0.f;
        for (int cp = 0; cp < c; cp++)
            hv = fmaf(wch[cp], Sb[(size_t)cp * 4096 + idx], hv);
        sH[r][n] = hv;
        int d0 = h * 64 + n, d2 = co + n;
        float a0 = cb[d0], a2 = cb[d2];
        float4 w0 = *(const float4*)(cw + d0 * 4);
        float4 w2 = *(const float4*)(cw + d2 * 4);
        #pragma unroll
        for (int k = 0; k < 4; k++){
            int dl = l + k - 3;
            if (dl >= 0){
                const float* zr = zb + (size_t)dl * zxs;
                a0 += zr[d0] * (&w0.x)[k];
                a2 += zr[d2] * (&w2.x)[k];
            }
        }
        sXc[r][n] = siluf(a0);
        sC[r][n] = siluf(a2);
    }
    if (tid < 64) scl[tid] = __expf(clb[(size_t)blk * 64 + tid]);
    float Dh = Dp[h];
    __syncthreads();
    int g1 = tid >> 4, g2 = tid & 15;
    int t0 = g1 * 4, p0 = g2 * 4;
    float m[4][4] = {};
    for (int n = 0; n < 64; n += 4){
        float4 cv[4], hv[4];
        #pragma unroll
        for (int i = 0; i < 4; i++) cv[i] = *(const float4*)&sC[t0 + i][n];
        #pragma unroll
        for (int j = 0; j < 4; j++) hv[j] = *(const float4*)&sH[p0 + j][n];
        #pragma unroll
        for (int i = 0; i < 4; i++)
            #pragma unroll
            for (int j = 0; j < 4; j++){
                m[i][j] = fmaf(cv[i].x, hv[j].x, m[i][j]);
                m[i][j] = fmaf(cv[i].y, hv[j].y, m[i][j]);
                m[i][j] = fmaf(cv[i].z, hv[j].z, m[i][j]);
                m[i][j] = fmaf(cv[i].w, hv[j].w, m[i][j]);
            }
    }
    #pragma unroll
    for (int i = 0; i < 4; i++){
        int t = t0 + i;
        size_t yi = (size_t)(b * L + l0 + t) * ys + h * 64 + p0;
        float4 yv = *(float4*)&y[yi];
        float4 xv = *(const float4*)&sXc[t][p0];
        float e = scl[t];
        yv.x += e * m[i][0] + Dh * xv.x;
        yv.y += e * m[i][1] + Dh * xv.y;
        yv.z += e * m[i][2] + Dh * xv.z;
        yv.w += e * m[i][3] + Dh * xv.w;
        *(float4*)&y[yi] = yv;
    }
}

// ---------- center projection + q ----------
__global__ void k_center_q(const float* __restrict__ xs, const float* __restrict__ cw,
                           const float* __restrict__ cb, const float* __restrict__ qw,
                           const float* __restrict__ qb, float* __restrict__ q){
    __shared__ float xr[640];
    __shared__ float cen[128];
    int b = blockIdx.x, t = threadIdx.x; // 128 thr
    for (int idx = t; idx < 640; idx += 128)
        xr[idx] = xs[(size_t)b * 256 * 128 + idx];
    __syncthreads();
    float acc = cb[t];
    for (int c = 0; c < 128; c++){
        const float* wp = cw + (size_t)(t * 128 + c) * 5;
        #pragma unroll
        for (int l = 0; l < 5; l++) acc += xr[l * 128 + c] * wp[l];
    }
    cen[t] = acc;
    __syncthreads();
    float qa = qb[t];
    const float* wr = qw + (size_t)t * 128;
    for (int o = 0; o < 128; o++) qa += cen[o] * wr[o];
    q[b * 128 + t] = qa;
}

// ---------- attention softmax over l ----------
__global__ void k_attn(const float* __restrict__ q, const float* __restrict__ k,
                       float* __restrict__ attn){
    __shared__ float sm[16];
    __shared__ float qh[16];
    int blk = blockIdx.x; int b = blk >> 3, h = blk & 7; int l = threadIdx.x; // 256 thr
    if (l < 16) qh[l] = q[b * 128 + h * 16 + l];
    __syncthreads();
    const float* kp = k + ((size_t)(b * 256 + l)) * 128 + h * 16;
    float s = 0.f;
    #pragma unroll
    for (int d = 0; d < 16; d++) s += qh[d] * kp[d];
    s *= 0.25f;
    float mx = blk_max1(s, sm);
    float e = __expf(s - mx);
    float sum = blk_sum1(e, sm);
    attn[(size_t)blk * 256 + l] = e / sum;
}

// ---------- attention out, 8 l-rows per block ----------
__global__ __launch_bounds__(128) void k_attn_out(const float* __restrict__ v,
                                                  const float* __restrict__ attn,
                                                  const float* __restrict__ owt,
                                                  const float* __restrict__ ob,
                                                  float* __restrict__ xs){
    __shared__ float vp[8][128];
    int blk = blockIdx.x; int b = blk >> 5, l0 = (blk & 31) << 3;
    int t = threadIdx.x; // 128 thr
    int h = t >> 4;
    float a[8];
    #pragma unroll
    for (int r = 0; r < 8; r++)
        a[r] = attn[((size_t)(b * 8 + h)) * 256 + l0 + r];
    #pragma unroll
    for (int r = 0; r < 8; r++)
        vp[r][t] = v[((size_t)(b * 256 + l0 + r)) * 128 + t] * a[r];
    __syncthreads();
    float acc[8];
    float bv = ob[t];
    #pragma unroll
    for (int r = 0; r < 8; r++) acc[r] = bv;
    for (int j = 0; j < 128; j++){
        float w = owt[j * 128 + t];
        #pragma unroll
        for (int r = 0; r < 8; r++) acc[r] = fmaf(vp[r][j], w, acc[r]);
    }
    #pragma unroll
    for (int r = 0; r < 8; r++)
        xs[((size_t)(b * 256 + l0 + r)) * 128 + t] += acc[r];
}

// ---------- fused spectral attention: QK+softmax+AV+SO+residual+unsort ----------
__global__ __launch_bounds__(256) void k_spe_attn(const float* __restrict__ q2,
        const float* __restrict__ k2t, const float* __restrict__ v2,
        const float* __restrict__ sowt, const float* __restrict__ sob,
        const float* __restrict__ xs, const int* __restrict__ sidx,
        float* __restrict__ xr){
    __shared__ float qs[8][256];
    __shared__ float lgp[2][8][128];
    __shared__ float sa[8][132];
    __shared__ float av[8][256];
    __shared__ float mxs[8], sms[8];
    int blk = blockIdx.x; int b = blk >> 4; int i0 = (blk & 15) << 3;
    int t = threadIdx.x;
    for (int idx = t; idx < 2048; idx += 256){
        int ii = idx >> 8, d = idx & 255;
        qs[ii][d] = q2[((size_t)(b * 128 + i0 + ii)) * 256 + d];
    }
    __syncthreads();
    {
        int j = t & 127, dh = t >> 7;
        const float* kt = k2t + (size_t)b * 32768 + dh * 16384;
        float acc[8] = {};
        for (int dd = 0; dd < 128; dd++){
            float kv = kt[dd * 128 + j];
            int d = dh * 128 + dd;
            #pragma unroll
            for (int ii = 0; ii < 8; ii++) acc[ii] = fmaf(qs[ii][d], kv, acc[ii]);
        }
        #pragma unroll
        for (int ii = 0; ii < 8; ii++) lgp[dh][ii][j] = acc[ii];
    }
    __syncthreads();
    if (t < 128){
        #pragma unroll
        for (int ii = 0; ii < 8; ii++)
            sa[ii][t] = (lgp[0][ii][t] + lgp[1][ii][t]) * (1.f / 16.f);
    }
    __syncthreads();
    if (t < 8){
        float mx = -3.4e38f;
        for (int j = 0; j < 128; j++) mx = fmaxf(mx, sa[t][j]);
        float sm = 0.f;
        for (int j = 0; j < 128; j++) sm += __expf(sa[t][j] - mx);
        mxs[t] = mx; sms[t] = 1.f / sm;
    }
    __syncthreads();
    if (t < 128){
        #pragma unroll
        for (int ii = 0; ii < 8; ii++)
            sa[ii][t] = __expf(sa[ii][t] - mxs[ii]) * sms[ii];
    }
    __syncthreads();
    {
        float acc[8] = {};
        const float* vb = v2 + (size_t)b * 32768 + t;
        for (int j = 0; j < 128; j++){
            float vv = vb[(size_t)j * 256];
            #pragma unroll
            for (int ii = 0; ii < 8; ii++) acc[ii] = fmaf(sa[ii][j], vv, acc[ii]);
        }
        #pragma unroll
        for (int ii = 0; ii < 8; ii++) av[ii][t] = acc[ii];
    }
    __syncthreads();
    float acc[8] = {};
    for (int d = 0; d < 256; d++){
        float wv = sowt[d * 256 + t];
        #pragma unroll
        for (int ii = 0; ii < 8; ii++) acc[ii] = fmaf(av[ii][d], wv, acc[ii]);
    }
    float bias = sob[t];
    int p = sidx[b * 256 + t];
    const float* xin = xs + ((size_t)(b * 256 + t)) * 128 + i0;
    float* xout = xr + ((size_t)(b * 256 + p)) * 128 + i0;
    #pragma unroll
    for (int ii = 0; ii < 8; ii++) xout[ii] = xin[ii] + acc[ii] + bias;
}

// ---------- conv GEMM split-K=4 with fused im2col (pipelined, fp32) ----------
__global__ __launch_bounds__(256) void k_conv_gemm(const float* __restrict__ xr,
                                                   const float* __restrict__ W2,
                                                   float* __restrict__ part){
    __shared__ float As[16][68];
    __shared__ float Ws[16][64];
    int j0 = blockIdx.x * 64, r0 = blockIdx.y * 64, s = blockIdx.z;
    int tid = threadIdx.x;
    int cg = tid & 15, rg = tid >> 4;
    int arow = tid >> 2, akg = tid & 3;
    int wkk = tid >> 4, wseg = tid & 15;
    int r = r0 + arow; int b = r >> 6, oh = (r >> 3) & 7, ow = r & 7;
    float acc[4][4] = {};
    int kbeg = s * 288, kend = kbeg + 288;
    float4 a4, w4;
    {
        int k = kbeg + akg * 4;
        int khw = k >> 7, c = k & 127;
        int kh = khw / 3, kw = khw - kh * 3;
        int ih = oh * 2 - 1 + kh, iw = ow * 2 - 1 + kw;
        a4 = make_float4(0.f, 0.f, 0.f, 0.f);
        if (ih >= 0 && ih < 16 && iw >= 0 && iw < 16)
            a4 = *(const float4*)(xr + ((size_t)((b << 8) + (ih << 4) + iw)) * 128 + c);
        w4 = *(const float4*)(W2 + (size_t)(kbeg + wkk) * 128 + j0 + wseg * 4);
    }
    for (int k0 = kbeg; k0 < kend; k0 += 16){
        __syncthreads();
        As[akg * 4 + 0][arow] = a4.x; As[akg * 4 + 1][arow] = a4.y;
        As[akg * 4 + 2][arow] = a4.z; As[akg * 4 + 3][arow] = a4.w;
        Ws[wkk][wseg * 4 + 0] = w4.x; Ws[wkk][wseg * 4 + 1] = w4.y;
        Ws[wkk][wseg * 4 + 2] = w4.z; Ws[wkk][wseg * 4 + 3] = w4.w;
        __syncthreads();
        bool more = (k0 + 16 < kend);
        float4 na4, nw4;
        if (more){
            int k = k0 + 16 + akg * 4;
            int khw = k >> 7, c = k & 127;
            int kh = khw / 3, kw = khw - kh * 3;
            int ih = oh * 2 - 1 + kh, iw = ow * 2 - 1 + kw;
            na4 = make_float4(0.f, 0.f, 0.f, 0.f);
            if (ih >= 0 && ih < 16 && iw >= 0 && iw < 16)
                na4 = *(const float4*)(xr + ((size_t)((b << 8) + (ih << 4) + iw)) * 128 + c);
            nw4 = *(const float4*)(W2 + (size_t)(k0 + 16 + wkk) * 128 + j0 + wseg * 4);
        }
        #pragma unroll
        for (int kk = 0; kk < 16; kk++){
            float4 av4 = *(const float4*)(&As[kk][rg << 2]);
            float4 wv4 = *(const float4*)(&Ws[kk][cg << 2]);
            float av_[4] = {av4.x, av4.y, av4.z, av4.w};
            float wv_[4] = {wv4.x, wv4.y, wv4.z, wv4.w};
            #pragma unroll
            for (int ri = 0; ri < 4; ri++)
                #pragma unroll
                for (int ci = 0; ci < 4; ci++)
                    acc[ri][ci] = fmaf(av_[ri], wv_[ci], acc[ri][ci]);
        }
        if (more){ a4 = na4; w4 = nw4; }
    }
    float* pp = part + (size_t)s * 1024 * 128;
    #pragma unroll
    for (int ri = 0; ri < 4; ri++){
        int rr = r0 + (rg << 2) + ri;
        #pragma unroll
        for (int ci = 0; ci < 4; ci++){
            int j = j0 + (cg << 2) + ci;
            pp[(size_t)rr * 128 + j] = acc[ri][ci];
        }
    }
}

// ---------- reduce split-K partials + LayerNorm ----------
__global__ void k_part_ln(const float* __restrict__ part, const float* __restrict__ lnw,
                          const float* __restrict__ lnb, float* __restrict__ out){
    __shared__ float sm[16];
    int r = blockIdx.x, t = threadIdx.x; // 128 thr
    float v = part[(size_t)r * 128 + t]
            + part[(size_t)(1024 + r) * 128 + t]
            + part[(size_t)(2048 + r) * 128 + t]
            + part[(size_t)(3072 + r) * 128 + t];
    float a = v, q = v * v;
    blk_sum2(a, q, sm);
    float mu = a * (1.f / 128.f);
    float var = q * (1.f / 128.f) - mu * mu;
    float rs = rsqrtf(var + 1e-5f);
    out[(size_t)r * 128 + t] = (v - mu) * rs * lnw[t] + lnb[t];
}

extern "C" void kernel_launch(void* const* d_in, const int* in_sizes, int n_in,
                              void* d_out, int out_size, void* d_ws, size_t ws_size,
                              hipStream_t stream) {
    const float* x          = (const float*)d_in[0];
    const int*   sidx       = (const int*)  d_in[1];
    const float* spa_ln_w   = (const float*)d_in[2];
    const float* spa_ln_b   = (const float*)d_in[3];
    const float* spa_in_w   = (const float*)d_in[4];
    const float* spa_conv_w = (const float*)d_in[5];
    const float* spa_conv_b = (const float*)d_in[6];
    const float* spa_dt_bias= (const float*)d_in[7];
    const float* spa_A_log  = (const float*)d_in[8];
    const float* spa_D      = (const float*)d_in[9];
    const float* spa_rms_w  = (const float*)d_in[10];
    const float* spa_out_w  = (const float*)d_in[11];
    const float* spe_ln_w   = (const float*)d_in[12];
    const float* spe_ln_b   = (const float*)d_in[13];
    const float* spe_in_w   = (const float*)d_in[14];
    const float* spe_conv_w = (const float*)d_in[15];
    const float* spe_conv_b = (const float*)d_in[16];
    const float* spe_dt_bias= (const float*)d_in[17];
    const float* spe_A_log  = (const float*)d_in[18];
    const float* spe_D      = (const float*)d_in[19];
    const float* spe_rms_w  = (const float*)d_in[20];
    const float* spe_out_w  = (const float*)d_in[21];
    const float* norm_w     = (const float*)d_in[22];
    const float* norm_b     = (const float*)d_in[23];
    const float* cprj_w     = (const float*)d_in[24];
    const float* cprj_b     = (const float*)d_in[25];
    const float* aq_w       = (const float*)d_in[26];
    const float* aq_b       = (const float*)d_in[27];
    const float* ak_w       = (const float*)d_in[28];
    const float* ak_b       = (const float*)d_in[29];
    const float* av_w       = (const float*)d_in[30];
    const float* av_b       = (const float*)d_in[31];
    const float* ao_w       = (const float*)d_in[32];
    const float* ao_b       = (const float*)d_in[33];
    const float* sq_w       = (const float*)d_in[34];
    const float* sq_b       = (const float*)d_in[35];
    const float* sk_w       = (const float*)d_in[36];
    const float* sk_b       = (const float*)d_in[37];
    const float* sv_w       = (const float*)d_in[38];
    const float* sv_b       = (const float*)d_in[39];
    const float* so_w       = (const float*)d_in[40];
    const float* so_b       = (const float*)d_in[41];
    const float* ds_conv_w  = (const float*)d_in[42];
    const float* ds_ln_w    = (const float*)d_in[43];
    const float* ds_ln_b    = (const float*)d_in[44];

    float* ws = (float*)d_ws;
    // loop-live arena: 0 .. 7946240
    float* xs   = ws + 0;        // 524288
    float* zx   = ws + 1048576;  // -> 3686400
    float* yb   = ws + 5324800;  // -> 6373376
    float* Sbuf = ws + 6373376;  // -> 7421952
    float* h1   = ws + 7421952;  // -> 7946240
    float* clbuf = ws + 524288;  // scratch (dead between uses)
    float* xT    = ws + 524288;  // scratch (dead after k_embed)
    // h1t aliases Sbuf: written by spatial gemm_gate AFTER chunk_y's last S read,
    // consumed by spectral gemm_ln BEFORE spectral ssd_chunk rewrites Sbuf.
    float* h1t   = ws + 6373376;
    // weight transposes: PAST the loop-live arena
    float* owt   = ws + 7946240; // 16384 -> 7962624
    float* sowt  = ws + 7962624; // 65536 -> 8028160
    // attention-stage aliases (host regions dead post-loop)
    float* kb    = ws + 1048576;
    float* vb    = ws + 1572864;
    float* attnb = ws + 2097152;
    float* qb    = ws + 2129920;
    float* xt    = ws + 524288;
    float* q2    = ws + 3686400;
    float* k2t   = ws + 4210688;
    float* v2    = ws + 4734976;
    float* xr    = ws + 5586944; // -> 6111232
    float* part  = ws + 1048576; // kb/vb region, dead by conv_gemm

    k_tr_multi<<<592, 256, 0, stream>>>(x, xT, ao_w, owt, so_w, sowt);
    k_embed<<<4096, 128, 0, stream>>>(xT, sidx, xs);

    for (int i = 0; i < 2; i++){
        // ---- spatial mamba (L=256, nh=4, nc=4; zxs=644, zoff=256, dtcol=640) ----
        k_gemm_ln<<<dim3(11, 64), 256, 0, stream>>>(xs, spa_in_w + (size_t)i * 644 * 128,
                                                    spa_ln_w + i * 128, spa_ln_b + i * 128,
                                                    zx, 644, 128);
        k_ssd_chunk<<<256, 256, 0, stream>>>(zx, spa_conv_w + (size_t)i * 384 * 4,
                                             spa_conv_b + i * 384, spa_dt_bias + i * 4,
                                             spa_A_log + i * 4, yb, Sbuf, clbuf,
                                             256, 4, 4, 644, 256, 256, 320, 640, 256);
        k_chunk_y<<<256, 256, 0, stream>>>(zx, spa_conv_w + (size_t)i * 384 * 4,
                                           spa_conv_b + i * 384, Sbuf, clbuf,
                                           spa_D + i * 4, yb,
                                           256, 4, 4, 644, 256, 320, 256);
        k_gemm_gate<<<dim3(2, 64), 256, 0, stream>>>(yb, zx, spa_rms_w + i * 256,
                                                     spa_out_w + (size_t)i * 128 * 256,
                                                     xs, h1, h1t, 128, 256, 644, 4);
        // ---- spectral mamba (L=128, nh=8, nc=2; zxs=1160, zoff=512, dtcol=1152) ----
        k_gemm_ln<<<dim3(19, 32), 256, 0, stream>>>(h1t, spe_in_w + (size_t)i * 1160 * 256,
                                                    spe_ln_w + i * 256, spe_ln_b + i * 256,
                                                    zx, 1160, 256);
        k_ssd_chunk<<<256, 256, 0, stream>>>(zx, spe_conv_w + (size_t)i * 640 * 4,
                                             spe_conv_b + i * 640, spe_dt_bias + i * 8,
                                             spe_A_log + i * 8, yb, Sbuf, clbuf,
                                             128, 8, 2, 1160, 512, 512, 576, 1152, 512);
        k_chunk_y<<<256, 256, 0, stream>>>(zx, spe_conv_w + (size_t)i * 640 * 4,
                                           spe_conv_b + i * 640, Sbuf, clbuf,
                                           spe_D + i * 8, yb,
                                           128, 8, 2, 1160, 512, 576, 512);
        k_gemm_gate<<<dim3(4, 32), 256, 0, stream>>>(yb, zx, spe_rms_w + i * 512,
                                                     spe_out_w + (size_t)i * 256 * 512,
                                                     h1, xs, nullptr, 256, 512, 1160, 2);
    }

    k_ln<<<4096, 128, 0, stream>>>(xs, norm_w, norm_b, xs, 128);
    k_center_q<<<16, 128, 0, stream>>>(xs, cprj_w, cprj_b, aq_w, aq_b, qb);
    {
        GJob jk = {ak_w, ak_b, kb, 0};
        GJob jv = {av_w, av_b, vb, 0};
        k_gemm3<<<dim3(2, 64, 2), 256, 0, stream>>>(xs, jk, jv, jk, 128, 128);
    }
    k_attn<<<128, 256, 0, stream>>>(qb, kb, attnb);
    k_attn_out<<<512, 128, 0, stream>>>(vb, attnb, owt, ao_b, xs);
    k_tr<<<dim3(4, 8, 16), 256, 0, stream>>>(xs, xt, 256, 128);
    {
        GJob jq = {sq_w, sq_b, q2, 0};
        GJob jk = {sk_w, sk_b, k2t, 3};
        GJob jv = {sv_w, sv_b, v2, 0};
        k_gemm3<<<dim3(4, 32, 3), 256, 0, stream>>>(xt, jq, jk, jv, 256, 256);
    }
    k_spe_attn<<<256, 256, 0, stream>>>(q2, k2t, v2, sowt, so_b, xs, sidx, xr);
    k_conv_gemm<<<dim3(2, 16, 4), 256, 0, stream>>>(xr, ds_conv_w, part);
    k_part_ln<<<1024, 128, 0, stream>>>(part, ds_ln_w, ds_ln_b, (float*)d_out);
}

// Round 15
// 551.953 us; speedup vs baseline: 1.1146x; 1.1146x over previous
//
#include <hip/hip_runtime.h>
#include <math.h>

#define DEV __device__ __forceinline__

typedef __attribute__((ext_vector_type(8))) short short8;
typedef __attribute__((ext_vector_type(4))) float f32x4;
typedef unsigned short ushort_t;
typedef unsigned int uint_t;

DEV float siluf(float x){ return x / (1.f + __expf(-x)); }
DEV float softplusf(float x){ return (x > 20.f) ? x : log1pf(__expf(x)); }

DEV ushort_t bf16r(float f){
    uint_t u = __float_as_uint(f);
    return (ushort_t)((u + 0x7fffu + ((u >> 16) & 1u)) >> 16);
}
DEV uint_t pack2(float a, float b){
    return (uint_t)bf16r(a) | ((uint_t)bf16r(b) << 16);
}

// ---------- block reduction helpers (wave64) ----------
DEV void blk_sum2(float &a, float &b, float* sm){
    int lane = threadIdx.x & 63, wid = threadIdx.x >> 6, nw = blockDim.x >> 6;
    #pragma unroll
    for (int off = 32; off; off >>= 1){ a += __shfl_down(a, off); b += __shfl_down(b, off); }
    if (lane == 0){ sm[wid] = a; sm[8 + wid] = b; }
    __syncthreads();
    float ra = 0.f, rb = 0.f;
    for (int i = 0; i < nw; i++){ ra += sm[i]; rb += sm[8 + i]; }
    __syncthreads();
    a = ra; b = rb;
}
DEV float blk_sum1(float v, float* sm){
    int lane = threadIdx.x & 63, wid = threadIdx.x >> 6, nw = blockDim.x >> 6;
    #pragma unroll
    for (int off = 32; off; off >>= 1) v += __shfl_down(v, off);
    if (lane == 0) sm[wid] = v;
    __syncthreads();
    float r = 0.f;
    for (int i = 0; i < nw; i++) r += sm[i];
    __syncthreads();
    return r;
}
DEV float blk_max1(float v, float* sm){
    int lane = threadIdx.x & 63, wid = threadIdx.x >> 6, nw = blockDim.x >> 6;
    #pragma unroll
    for (int off = 32; off; off >>= 1) v = fmaxf(v, __shfl_down(v, off));
    if (lane == 0) sm[wid] = v;
    __syncthreads();
    float r = -3.4e38f;
    for (int i = 0; i < nw; i++) r = fmaxf(r, sm[i]);
    __syncthreads();
    return r;
}

// ---------- transpose body ----------
DEV void tr_body(const float* __restrict__ ip, float* __restrict__ op,
                 int R, int C, int c0, int r0){
    __shared__ float tile[32][33];
    int tx = threadIdx.x & 31, ty = threadIdx.x >> 5;
    #pragma unroll
    for (int rr = ty; rr < 32; rr += 8)
        tile[rr][tx] = ip[(size_t)(r0 + rr) * C + c0 + tx];
    __syncthreads();
    #pragma unroll
    for (int rr = ty; rr < 32; rr += 8)
        op[(size_t)(c0 + rr) * R + r0 + tx] = tile[tx][rr];
}

__global__ __launch_bounds__(256) void k_tr(const float* __restrict__ in,
                                            float* __restrict__ out, int R, int C){
    tr_body(in + (size_t)blockIdx.z * R * C, out + (size_t)blockIdx.z * R * C,
            R, C, blockIdx.x * 32, blockIdx.y * 32);
}

// packed: job0 x->xT (512 blks), job1 ao_w (16), job2 so_w (64)
__global__ __launch_bounds__(256) void k_tr_multi(const float* __restrict__ x,
        float* __restrict__ xT, const float* __restrict__ aow, float* __restrict__ owt,
        const float* __restrict__ sow, float* __restrict__ sowt){
    int idx = blockIdx.x;
    if (idx < 512){
        int bx = idx & 7, by = (idx >> 3) & 3, bz = idx >> 5;
        tr_body(x + (size_t)bz * 32768, xT + (size_t)bz * 32768, 128, 256, bx * 32, by * 32);
    } else if (idx < 528){
        int l = idx - 512;
        tr_body(aow, owt, 128, 128, (l & 3) * 32, (l >> 2) * 32);
    } else {
        int l = idx - 528;
        tr_body(sow, sowt, 256, 256, (l & 7) * 32, (l >> 3) * 32);
    }
}

// ---------- K1: pos-embed + gather ----------
__global__ void k_embed(const float* __restrict__ xT, const int* __restrict__ sidx,
                        float* __restrict__ xs){
    int bl = blockIdx.x; int b = bl >> 8; int c = threadIdx.x;
    int p = sidx[bl];
    int hh = p >> 4, ww = p & 15;
    int pos = (c < 64) ? hh : ww;
    int jm = c & 63;
    float om = __expf(-(float)(jm & 31) * 0.28782313662425574f); // ln(10000)/32
    float ang = (float)pos * om;
    float pe = (jm < 32) ? sinf(ang) : cosf(ang);
    xs[(size_t)bl * 128 + c] = xT[((size_t)(b * 256 + p)) * 128 + c] + pe;
}

// ---------- LayerNorm (block per row) ----------
__global__ void k_ln(const float* __restrict__ in, const float* __restrict__ w,
                     const float* __restrict__ bb, float* __restrict__ out, int dim){
    __shared__ float sm[16];
    int row = blockIdx.x, t = threadIdx.x;
    float v = in[(size_t)row * dim + t];
    float a = v, q = v * v;
    blk_sum2(a, q, sm);
    float inv = 1.f / (float)dim;
    float mu = a * inv;
    float var = q * inv - mu * mu;
    float rs = rsqrtf(var + 1e-5f);
    out[(size_t)row * dim + t] = (v - mu) * rs * w[t] + bb[t];
}

// ======================================================================
// bf16 MFMA GEMM family: 64x64 tile, 256 thr = 4 waves.
// A/B frag: elem [lane&15][quad*8+j]; C/D: col=lane&15, row=quad*4+reg.
// ======================================================================

// ---------- in-projection GEMM with fused LayerNorm (bf16 MFMA) ----------
__global__ __launch_bounds__(256) void k_gemm_ln(const float* __restrict__ A,
        const float* __restrict__ W, const float* __restrict__ lw,
        const float* __restrict__ lb, float* __restrict__ out, int N, int K){
    __shared__ __align__(16) ushort_t smem[2 * 64 * 72];
    ushort_t (*Abf)[72] = (ushort_t (*)[72])smem;
    ushort_t (*Wbf)[72] = (ushort_t (*)[72])(smem + 64 * 72);
    int j0 = blockIdx.x * 64, r0 = blockIdx.y * 64;
    int tid = threadIdx.x;
    int row = tid >> 2, kg = tid & 3;
    int wrow = j0 + row; if (wrow > N - 1) wrow = N - 1;
    const float* Ar = A + (size_t)(r0 + row) * K;
    const float* Wr = W + (size_t)wrow * K;
    float s = 0.f, ss = 0.f;
    for (int k0 = 0; k0 < K; k0 += 32){
        float4 a0 = *(const float4*)(Ar + k0 + kg * 4);
        float4 a1 = *(const float4*)(Ar + k0 + 16 + kg * 4);
        s  += a0.x + a0.y + a0.z + a0.w + a1.x + a1.y + a1.z + a1.w;
        ss += a0.x*a0.x + a0.y*a0.y + a0.z*a0.z + a0.w*a0.w
            + a1.x*a1.x + a1.y*a1.y + a1.z*a1.z + a1.w*a1.w;
    }
    s  += __shfl_xor(s, 1);  ss += __shfl_xor(ss, 1);
    s  += __shfl_xor(s, 2);  ss += __shfl_xor(ss, 2);
    float inv = 1.f / (float)K;
    float mu = s * inv;
    float rs = rsqrtf(ss * inv - mu * mu + 1e-5f);
    int wv = tid >> 6, lane = tid & 63, lm = lane & 15, quad = lane >> 4;
    f32x4 zero4 = {0.f, 0.f, 0.f, 0.f};
    f32x4 acc[4] = {zero4, zero4, zero4, zero4};
    for (int kc0 = 0; kc0 < K; kc0 += 64){
        int kb = kc0 + kg * 16;
        float4 q[4], g[4], b[4], p[4];
        #pragma unroll
        for (int i = 0; i < 4; i++){
            q[i] = *(const float4*)(Ar + kb + i * 4);
            g[i] = *(const float4*)(lw + kb + i * 4);
            b[i] = *(const float4*)(lb + kb + i * 4);
            p[i] = *(const float4*)(Wr + kb + i * 4);
        }
        #pragma unroll
        for (int i = 0; i < 4; i++){
            q[i].x = (q[i].x - mu) * rs * g[i].x + b[i].x;
            q[i].y = (q[i].y - mu) * rs * g[i].y + b[i].y;
            q[i].z = (q[i].z - mu) * rs * g[i].z + b[i].z;
            q[i].w = (q[i].w - mu) * rs * g[i].w + b[i].w;
        }
        __syncthreads();
        {
            uint4 u0, u1;
            u0.x = pack2(q[0].x, q[0].y); u0.y = pack2(q[0].z, q[0].w);
            u0.z = pack2(q[1].x, q[1].y); u0.w = pack2(q[1].z, q[1].w);
            u1.x = pack2(q[2].x, q[2].y); u1.y = pack2(q[2].z, q[2].w);
            u1.z = pack2(q[3].x, q[3].y); u1.w = pack2(q[3].z, q[3].w);
            *(uint4*)&Abf[row][kg * 16] = u0;
            *(uint4*)&Abf[row][kg * 16 + 8] = u1;
            u0.x = pack2(p[0].x, p[0].y); u0.y = pack2(p[0].z, p[0].w);
            u0.z = pack2(p[1].x, p[1].y); u0.w = pack2(p[1].z, p[1].w);
            u1.x = pack2(p[2].x, p[2].y); u1.y = pack2(p[2].z, p[2].w);
            u1.z = pack2(p[3].x, p[3].y); u1.w = pack2(p[3].z, p[3].w);
            *(uint4*)&Wbf[row][kg * 16] = u0;
            *(uint4*)&Wbf[row][kg * 16 + 8] = u1;
        }
        __syncthreads();
        #pragma unroll
        for (int kk = 0; kk < 64; kk += 32){
            short8 af = *(const short8*)&Abf[wv * 16 + lm][kk + quad * 8];
            #pragma unroll
            for (int c = 0; c < 4; c++){
                short8 bfv = *(const short8*)&Wbf[c * 16 + lm][kk + quad * 8];
                acc[c] = __builtin_amdgcn_mfma_f32_16x16x32_bf16(af, bfv, acc[c], 0, 0, 0);
            }
        }
    }
    int rbase = r0 + wv * 16 + quad * 4;
    #pragma unroll
    for (int c = 0; c < 4; c++){
        int j = j0 + c * 16 + lm;
        if (j < N){
            #pragma unroll
            for (int reg = 0; reg < 4; reg++)
                out[(size_t)(rbase + reg) * N + j] = acc[c][reg];
        }
    }
}

// ---------- out-projection GEMM, fused gate(silu)+RMS (bf16 MFMA) ----------
// mode 1: out[r*N+j] = .*scale + res
// mode 2: transposed scatter (N==256): out[((r0>>7)*256+j)*128+(r&127)] = . + res
// mode 4: mode 1 + ALSO write out2 (h1t) transposed: out2[(b*128+j)*256+l] = same value
__global__ __launch_bounds__(256) void k_gemm_gate(const float* __restrict__ Y,
        const float* __restrict__ Z, const float* __restrict__ rw,
        const float* __restrict__ W, const float* __restrict__ res,
        float* __restrict__ out, float* __restrict__ out2,
        int N, int K, int zs, int mode){
    __shared__ __align__(16) ushort_t smem[2 * 64 * 72];
    ushort_t (*Abf)[72] = (ushort_t (*)[72])smem;
    ushort_t (*Wbf)[72] = (ushort_t (*)[72])(smem + 64 * 72);
    __shared__ float sscale[64];
    int j0 = blockIdx.x * 64, r0 = blockIdx.y * 64;
    int tid = threadIdx.x;
    int row = tid >> 2, kg = tid & 3;
    const float* Yr = Y + (size_t)(r0 + row) * K;
    const float* Zr = Z + (size_t)(r0 + row) * zs;
    const float* Wr = W + (size_t)(j0 + row) * K;
    int wv = tid >> 6, lane = tid & 63, lm = lane & 15, quad = lane >> 4;
    float ssq = 0.f;
    f32x4 zero4 = {0.f, 0.f, 0.f, 0.f};
    f32x4 acc[4] = {zero4, zero4, zero4, zero4};
    for (int kc0 = 0; kc0 < K; kc0 += 64){
        int kb = kc0 + kg * 16;
        float4 y[4], z[4], g[4], p[4];
        #pragma unroll
        for (int i = 0; i < 4; i++){
            y[i] = *(const float4*)(Yr + kb + i * 4);
            z[i] = *(const float4*)(Zr + kb + i * 4);
            g[i] = *(const float4*)(rw + kb + i * 4);
            p[i] = *(const float4*)(Wr + kb + i * 4);
        }
        #pragma unroll
        for (int i = 0; i < 4; i++){
            y[i].x *= siluf(z[i].x); y[i].y *= siluf(z[i].y);
            y[i].z *= siluf(z[i].z); y[i].w *= siluf(z[i].w);
            ssq += y[i].x*y[i].x + y[i].y*y[i].y + y[i].z*y[i].z + y[i].w*y[i].w;
            y[i].x *= g[i].x; y[i].y *= g[i].y; y[i].z *= g[i].z; y[i].w *= g[i].w;
        }
        __syncthreads();
        {
            uint4 u0, u1;
            u0.x = pack2(y[0].x, y[0].y); u0.y = pack2(y[0].z, y[0].w);
            u0.z = pack2(y[1].x, y[1].y); u0.w = pack2(y[1].z, y[1].w);
            u1.x = pack2(y[2].x, y[2].y); u1.y = pack2(y[2].z, y[2].w);
            u1.z = pack2(y[3].x, y[3].y); u1.w = pack2(y[3].z, y[3].w);
            *(uint4*)&Abf[row][kg * 16] = u0;
            *(uint4*)&Abf[row][kg * 16 + 8] = u1;
            u0.x = pack2(p[0].x, p[0].y); u0.y = pack2(p[0].z, p[0].w);
            u0.z = pack2(p[1].x, p[1].y); u0.w = pack2(p[1].z, p[1].w);
            u1.x = pack2(p[2].x, p[2].y); u1.y = pack2(p[2].z, p[2].w);
            u1.z = pack2(p[3].x, p[3].y); u1.w = pack2(p[3].z, p[3].w);
            *(uint4*)&Wbf[row][kg * 16] = u0;
            *(uint4*)&Wbf[row][kg * 16 + 8] = u1;
        }
        __syncthreads();
        #pragma unroll
        for (int kk = 0; kk < 64; kk += 32){
            short8 af = *(const short8*)&Abf[wv * 16 + lm][kk + quad * 8];
            #pragma unroll
            for (int c = 0; c < 4; c++){
                short8 bfv = *(const short8*)&Wbf[c * 16 + lm][kk + quad * 8];
                acc[c] = __builtin_amdgcn_mfma_f32_16x16x32_bf16(af, bfv, acc[c], 0, 0, 0);
            }
        }
    }
    ssq += __shfl_xor(ssq, 1);
    ssq += __shfl_xor(ssq, 2);
    if (kg == 0) sscale[row] = rsqrtf(ssq / (float)K + 1e-5f);
    __syncthreads(); // sscale visible; all LDS fragment reads done
    int lr0 = wv * 16 + quad * 4;
    float scr[4];
    #pragma unroll
    for (int reg = 0; reg < 4; reg++) scr[reg] = sscale[lr0 + reg];
    if (mode == 2){
        float (*T)[68] = (float (*)[68])smem;
        #pragma unroll
        for (int c = 0; c < 4; c++)
            #pragma unroll
            for (int reg = 0; reg < 4; reg++)
                T[c * 16 + lm][lr0 + reg] = acc[c][reg] * scr[reg];
        __syncthreads();
        int b2 = r0 >> 7, ii0 = r0 & 127;
        int jj = tid >> 2, seg = tid & 3;
        size_t base = ((size_t)(b2 * 256 + j0 + jj)) * 128 + ii0 + seg * 16;
        float* op = out + base;
        const float* rp = res + base;
        #pragma unroll
        for (int c = 0; c < 4; c++){
            float4 v = *(const float4*)(&T[jj][seg * 16 + c * 4]);
            float4 rv = *(const float4*)(rp + c * 4);
            v.x += rv.x; v.y += rv.y; v.z += rv.z; v.w += rv.w;
            *(float4*)(op + c * 4) = v;
        }
    } else { // mode 1 or 4
        float (*T)[68] = (float (*)[68])smem;
        int rbase = r0 + lr0;
        #pragma unroll
        for (int c = 0; c < 4; c++){
            int j = j0 + c * 16 + lm;
            #pragma unroll
            for (int reg = 0; reg < 4; reg++){
                size_t oi = (size_t)(rbase + reg) * N + j;
                float v = acc[c][reg] * scr[reg] + res[oi];
                out[oi] = v;
                if (mode == 4) T[c * 16 + lm][lr0 + reg] = v;
            }
        }
        if (mode == 4){
            __syncthreads();
            int bb = r0 >> 8, lbase = r0 & 255;
            int jj = tid >> 2, seg = tid & 3;
            size_t base2 = ((size_t)(bb * 128 + j0 + jj)) * 256 + lbase + seg * 16;
            float* op = out2 + base2;
            #pragma unroll
            for (int cc = 0; cc < 4; cc++){
                float4 v = *(const float4*)(&T[jj][seg * 16 + cc * 4]);
                *(float4*)(op + cc * 4) = v;
            }
        }
    }
}

// ---------- qkv GEMM (bf16 MFMA), mode 0: +bias; mode 3: transposed+bias ----------
struct GJob { const float* W; const float* bias; float* out; int mode; };

__global__ __launch_bounds__(256) void k_gemm3(const float* __restrict__ A,
                                               GJob ja, GJob jb, GJob jc,
                                               int N, int K){
    GJob job = (blockIdx.z == 0) ? ja : ((blockIdx.z == 1) ? jb : jc);
    const float* W = job.W;
    const float* bias = job.bias;
    float* out = job.out;
    int mode = job.mode;
    __shared__ __align__(16) ushort_t smem[2 * 64 * 72];
    ushort_t (*Abf)[72] = (ushort_t (*)[72])smem;
    ushort_t (*Wbf)[72] = (ushort_t (*)[72])(smem + 64 * 72);
    int j0 = blockIdx.x * 64, r0 = blockIdx.y * 64;
    int tid = threadIdx.x;
    int row = tid >> 2, kg = tid & 3;
    const float* Ar = A + (size_t)(r0 + row) * K;
    const float* Wr = W + (size_t)(j0 + row) * K;
    int wv = tid >> 6, lane = tid & 63, lm = lane & 15, quad = lane >> 4;
    f32x4 zero4 = {0.f, 0.f, 0.f, 0.f};
    f32x4 acc[4] = {zero4, zero4, zero4, zero4};
    for (int kc0 = 0; kc0 < K; kc0 += 64){
        int kb = kc0 + kg * 16;
        float4 q[4], p[4];
        #pragma unroll
        for (int i = 0; i < 4; i++){
            q[i] = *(const float4*)(Ar + kb + i * 4);
            p[i] = *(const float4*)(Wr + kb + i * 4);
        }
        __syncthreads();
        {
            uint4 u0, u1;
            u0.x = pack2(q[0].x, q[0].y); u0.y = pack2(q[0].z, q[0].w);
            u0.z = pack2(q[1].x, q[1].y); u0.w = pack2(q[1].z, q[1].w);
            u1.x = pack2(q[2].x, q[2].y); u1.y = pack2(q[2].z, q[2].w);
            u1.z = pack2(q[3].x, q[3].y); u1.w = pack2(q[3].z, q[3].w);
            *(uint4*)&Abf[row][kg * 16] = u0;
            *(uint4*)&Abf[row][kg * 16 + 8] = u1;
            u0.x = pack2(p[0].x, p[0].y); u0.y = pack2(p[0].z, p[0].w);
            u0.z = pack2(p[1].x, p[1].y); u0.w = pack2(p[1].z, p[1].w);
            u1.x = pack2(p[2].x, p[2].y); u1.y = pack2(p[2].z, p[2].w);
            u1.z = pack2(p[3].x, p[3].y); u1.w = pack2(p[3].z, p[3].w);
            *(uint4*)&Wbf[row][kg * 16] = u0;
            *(uint4*)&Wbf[row][kg * 16 + 8] = u1;
        }
        __syncthreads();
        #pragma unroll
        for (int kk = 0; kk < 64; kk += 32){
            short8 af = *(const short8*)&Abf[wv * 16 + lm][kk + quad * 8];
            #pragma unroll
            for (int c = 0; c < 4; c++){
                short8 bfv = *(const short8*)&Wbf[c * 16 + lm][kk + quad * 8];
                acc[c] = __builtin_amdgcn_mfma_f32_16x16x32_bf16(af, bfv, acc[c], 0, 0, 0);
            }
        }
    }
    int lr0 = wv * 16 + quad * 4;
    if (mode == 3){
        __syncthreads();
        float (*T)[68] = (float (*)[68])smem;
        #pragma unroll
        for (int c = 0; c < 4; c++)
            #pragma unroll
            for (int reg = 0; reg < 4; reg++)
                T[c * 16 + lm][lr0 + reg] = acc[c][reg];
        __syncthreads();
        int b2 = r0 >> 7, ii0 = r0 & 127;
        int jj = tid >> 2, seg = tid & 3;
        size_t base = ((size_t)(b2 * 256 + j0 + jj)) * 128 + ii0 + seg * 16;
        float* op = out + base;
        float bj = bias[j0 + jj];
        #pragma unroll
        for (int c = 0; c < 4; c++){
            float4 v = *(const float4*)(&T[jj][seg * 16 + c * 4]);
            v.x += bj; v.y += bj; v.z += bj; v.w += bj;
            *(float4*)(op + c * 4) = v;
        }
    } else {
        int rbase = r0 + lr0;
        #pragma unroll
        for (int c = 0; c < 4; c++){
            int j = j0 + c * 16 + lm;
            float bj = bias[j];
            #pragma unroll
            for (int reg = 0; reg < 4; reg++)
                out[(size_t)(rbase + reg) * N + j] = acc[c][reg] + bj;
        }
    }
}

// ---------- causal depthwise conv(4)+bias+silu, fused dt / log-dA ----------
__global__ void k_conv(const float* __restrict__ zx, const float* __restrict__ cw,
                       const float* __restrict__ cb, float* __restrict__ xc,
                       const float* __restrict__ dtbias, const float* __restrict__ Al,
                       float* __restrict__ dt, float* __restrict__ dlA,
                       int L, int D, int stride, int off, int nh, int dtoff){
    int bl = blockIdx.x;
    int l = bl & (L - 1);
    const float* base = zx + (size_t)bl * stride + off;
    for (int d = threadIdx.x; d < D; d += blockDim.x){
        float acc = cb[d];
        #pragma unroll
        for (int k = 0; k < 4; k++){
            int dl = l + k - 3;
            if (dl >= 0) acc += base[(ptrdiff_t)(k - 3) * stride + d] * cw[d * 4 + k];
        }
        xc[(size_t)bl * D + d] = siluf(acc);
    }
    int t = threadIdx.x;
    if (t < nh){
        float xv = zx[(size_t)bl * stride + dtoff + t] + dtbias[t];
        float d = softplusf(xv);
        dt[(size_t)bl * nh + t] = d;
        dlA[(size_t)bl * nh + t] = -d * __expf(Al[t]); // log(dA) <= 0
    }
}

// ---------- chunked SSD, stage A ----------
__global__ __launch_bounds__(256) void k_ssd_chunk(
        const float* __restrict__ xc, const float* __restrict__ dt,
        const float* __restrict__ dlA, float* __restrict__ y,
        float* __restrict__ S, float* __restrict__ clb,
        int L, int nh, int nc, int xcs, int bo, int co, int ys){
    __shared__ float sX[64][68];
    __shared__ float sB[64][68];
    __shared__ float sC[64][68]; // phase1: C ; after: masked G
    __shared__ float cl[64], sdt[64], sw[64];
    int blk = blockIdx.x;
    int c = blk % nc; int bh = blk / nc; int h = bh % nh; int b = bh / nh;
    int l0 = c * 64;
    int tid = threadIdx.x;
    const float* base = xc + ((size_t)(b * L + l0)) * xcs;
    for (int idx = tid; idx < 4096; idx += 256){
        int s = idx >> 6, n = idx & 63;
        const float* row = base + (size_t)s * xcs;
        sX[s][n] = row[h * 64 + n];
        sB[s][n] = row[bo + n];
        sC[s][n] = row[co + n];
    }
    if (tid < 64){
        size_t di = (size_t)(b * L + l0 + tid) * nh + h;
        float dlv = dlA[di];
        sdt[tid] = dt[di];
        #pragma unroll
        for (int off = 1; off < 64; off <<= 1){
            float o = __shfl_up(dlv, off, 64);
            if (tid >= off) dlv += o;
        }
        cl[tid] = dlv;
        clb[(size_t)blk * 64 + tid] = dlv;
    }
    __syncthreads();
    if (tid < 64) sw[tid] = __expf(cl[63] - cl[tid]) * sdt[tid];

    int g1 = tid >> 4, g2 = tid & 15;
    int t0 = g1 * 4, s0 = g2 * 4;
    float g[4][4] = {};
    for (int n = 0; n < 64; n += 4){
        float4 cv[4], bv[4];
        #pragma unroll
        for (int i = 0; i < 4; i++) cv[i] = *(const float4*)&sC[t0 + i][n];
        #pragma unroll
        for (int j = 0; j < 4; j++) bv[j] = *(const float4*)&sB[s0 + j][n];
        #pragma unroll
        for (int i = 0; i < 4; i++)
            #pragma unroll
            for (int j = 0; j < 4; j++){
                g[i][j] = fmaf(cv[i].x, bv[j].x, g[i][j]);
                g[i][j] = fmaf(cv[i].y, bv[j].y, g[i][j]);
                g[i][j] = fmaf(cv[i].z, bv[j].z, g[i][j]);
                g[i][j] = fmaf(cv[i].w, bv[j].w, g[i][j]);
            }
    }
    __syncthreads();
    #pragma unroll
    for (int i = 0; i < 4; i++)
        #pragma unroll
        for (int j = 0; j < 4; j++){
            int t = t0 + i, s = s0 + j;
            float v = 0.f;
            if (s <= t) v = g[i][j] * __expf(cl[t] - cl[s]) * sdt[s];
            sC[t][s] = v;
        }
    __syncthreads();
    {
        float acc[4][4] = {};
        for (int s = 0; s < 64; s++){
            float4 xv = *(const float4*)&sX[s][s0];
            float gv[4];
            #pragma unroll
            for (int i = 0; i < 4; i++) gv[i] = sC[t0 + i][s];
            #pragma unroll
            for (int i = 0; i < 4; i++){
                acc[i][0] = fmaf(gv[i], xv.x, acc[i][0]);
                acc[i][1] = fmaf(gv[i], xv.y, acc[i][1]);
                acc[i][2] = fmaf(gv[i], xv.z, acc[i][2]);
                acc[i][3] = fmaf(gv[i], xv.w, acc[i][3]);
            }
        }
        #pragma unroll
        for (int i = 0; i < 4; i++){
            float4 o = make_float4(acc[i][0], acc[i][1], acc[i][2], acc[i][3]);
            *(float4*)&y[(size_t)(b * L + l0 + t0 + i) * ys + h * 64 + s0] = o;
        }
    }
    {
        float acc[4][4] = {};
        int p0 = t0, n0 = s0;
        for (int s = 0; s < 64; s++){
            float wv = sw[s];
            float4 bv = *(const float4*)&sB[s][n0];
            float4 xv = *(const float4*)&sX[s][p0];
            float w0 = wv * xv.x, w1 = wv * xv.y, w2 = wv * xv.z, w3 = wv * xv.w;
            acc[0][0] = fmaf(w0, bv.x, acc[0][0]); acc[0][1] = fmaf(w0, bv.y, acc[0][1]);
            acc[0][2] = fmaf(w0, bv.z, acc[0][2]); acc[0][3] = fmaf(w0, bv.w, acc[0][3]);
            acc[1][0] = fmaf(w1, bv.x, acc[1][0]); acc[1][1] = fmaf(w1, bv.y, acc[1][1]);
            acc[1][2] = fmaf(w1, bv.z, acc[1][2]); acc[1][3] = fmaf(w1, bv.w, acc[1][3]);
            acc[2][0] = fmaf(w2, bv.x, acc[2][0]); acc[2][1] = fmaf(w2, bv.y, acc[2][1]);
            acc[2][2] = fmaf(w2, bv.z, acc[2][2]); acc[2][3] = fmaf(w2, bv.w, acc[2][3]);
            acc[3][0] = fmaf(w3, bv.x, acc[3][0]); acc[3][1] = fmaf(w3, bv.y, acc[3][1]);
            acc[3][2] = fmaf(w3, bv.z, acc[3][2]); acc[3][3] = fmaf(w3, bv.w, acc[3][3]);
        }
        float* Sp = S + (size_t)blk * 4096;
        #pragma unroll
        for (int i = 0; i < 4; i++){
            float4 o = make_float4(acc[i][0], acc[i][1], acc[i][2], acc[i][3]);
            *(float4*)&Sp[(p0 + i) * 64 + n0] = o;
        }
    }
}

// ---------- chunked SSD, stage B+C fused ----------
__global__ __launch_bounds__(256) void k_chunk_y(
        const float* __restrict__ xc, const float* __restrict__ S,
        const float* __restrict__ clb, const float* __restrict__ Dp,
        float* __restrict__ y,
        int L, int nh, int nc, int xcs, int co, int ys){
    __shared__ float sH[64][68];
    __shared__ float sC[64][68];
    __shared__ float scl[64];
    int blk = blockIdx.x;
    int c = blk % nc; int bh = blk / nc; int h = bh % nh; int b = bh / nh;
    int l0 = c * 64;
    int tid = threadIdx.x;
    float wch[4];
    {
        float w = 1.f;
        for (int cp = c - 1; cp >= 0; cp--){
            wch[cp] = w;
            w *= __expf(clb[((size_t)(bh * nc + cp)) * 64 + 63]);
        }
    }
    const float* Sb = S + (size_t)(bh * nc) * 4096;
    const float* base = xc + ((size_t)(b * L + l0)) * xcs;
    for (int idx = tid; idx < 4096; idx += 256){
        int r = idx >> 6, n = idx & 63;
        float hv = 0.f;
        for (int cp = 0; cp < c; cp++)
            hv = fmaf(wch[cp], Sb[(size_t)cp * 4096 + idx], hv);
        sH[r][n] = hv;
        sC[r][n] = base[(size_t)r * xcs + co + n];
    }
    if (tid < 64) scl[tid] = __expf(clb[(size_t)blk * 64 + tid]);
    float Dh = Dp[h];
    __syncthreads();
    int g1 = tid >> 4, g2 = tid & 15;
    int t0 = g1 * 4, p0 = g2 * 4;
    float m[4][4] = {};
    for (int n = 0; n < 64; n += 4){
        float4 cv[4], hv[4];
        #pragma unroll
        for (int i = 0; i < 4; i++) cv[i] = *(const float4*)&sC[t0 + i][n];
        #pragma unroll
        for (int j = 0; j < 4; j++) hv[j] = *(const float4*)&sH[p0 + j][n];
        #pragma unroll
        for (int i = 0; i < 4; i++)
            #pragma unroll
            for (int j = 0; j < 4; j++){
                m[i][j] = fmaf(cv[i].x, hv[j].x, m[i][j]);
                m[i][j] = fmaf(cv[i].y, hv[j].y, m[i][j]);
                m[i][j] = fmaf(cv[i].z, hv[j].z, m[i][j]);
                m[i][j] = fmaf(cv[i].w, hv[j].w, m[i][j]);
            }
    }
    #pragma unroll
    for (int i = 0; i < 4; i++){
        int t = t0 + i;
        size_t yi = (size_t)(b * L + l0 + t) * ys + h * 64 + p0;
        float4 yv = *(float4*)&y[yi];
        float4 xv = *(const float4*)&base[(size_t)t * xcs + h * 64 + p0];
        float e = scl[t];
        yv.x += e * m[i][0] + Dh * xv.x;
        yv.y += e * m[i][1] + Dh * xv.y;
        yv.z += e * m[i][2] + Dh * xv.z;
        yv.w += e * m[i][3] + Dh * xv.w;
        *(float4*)&y[yi] = yv;
    }
}

// ---------- center projection + q ----------
__global__ void k_center_q(const float* __restrict__ xs, const float* __restrict__ cw,
                           const float* __restrict__ cb, const float* __restrict__ qw,
                           const float* __restrict__ qb, float* __restrict__ q){
    __shared__ float xr[640];
    __shared__ float cen[128];
    int b = blockIdx.x, t = threadIdx.x; // 128 thr
    for (int idx = t; idx < 640; idx += 128)
        xr[idx] = xs[(size_t)b * 256 * 128 + idx];
    __syncthreads();
    float acc = cb[t];
    for (int c = 0; c < 128; c++){
        const float* wp = cw + (size_t)(t * 128 + c) * 5;
        #pragma unroll
        for (int l = 0; l < 5; l++) acc += xr[l * 128 + c] * wp[l];
    }
    cen[t] = acc;
    __syncthreads();
    float qa = qb[t];
    const float* wr = qw + (size_t)t * 128;
    for (int o = 0; o < 128; o++) qa += cen[o] * wr[o];
    q[b * 128 + t] = qa;
}

// ---------- attention softmax over l ----------
__global__ void k_attn(const float* __restrict__ q, const float* __restrict__ k,
                       float* __restrict__ attn){
    __shared__ float sm[16];
    __shared__ float qh[16];
    int blk = blockIdx.x; int b = blk >> 3, h = blk & 7; int l = threadIdx.x; // 256 thr
    if (l < 16) qh[l] = q[b * 128 + h * 16 + l];
    __syncthreads();
    const float* kp = k + ((size_t)(b * 256 + l)) * 128 + h * 16;
    float s = 0.f;
    #pragma unroll
    for (int d = 0; d < 16; d++) s += qh[d] * kp[d];
    s *= 0.25f;
    float mx = blk_max1(s, sm);
    float e = __expf(s - mx);
    float sum = blk_sum1(e, sm);
    attn[(size_t)blk * 256 + l] = e / sum;
}

// ---------- attention out, 8 l-rows per block ----------
__global__ __launch_bounds__(128) void k_attn_out(const float* __restrict__ v,
                                                  const float* __restrict__ attn,
                                                  const float* __restrict__ owt,
                                                  const float* __restrict__ ob,
                                                  float* __restrict__ xs){
    __shared__ float vp[8][128];
    int blk = blockIdx.x; int b = blk >> 5, l0 = (blk & 31) << 3;
    int t = threadIdx.x; // 128 thr
    int h = t >> 4;
    float a[8];
    #pragma unroll
    for (int r = 0; r < 8; r++)
        a[r] = attn[((size_t)(b * 8 + h)) * 256 + l0 + r];
    #pragma unroll
    for (int r = 0; r < 8; r++)
        vp[r][t] = v[((size_t)(b * 256 + l0 + r)) * 128 + t] * a[r];
    __syncthreads();
    float acc[8];
    float bv = ob[t];
    #pragma unroll
    for (int r = 0; r < 8; r++) acc[r] = bv;
    for (int j = 0; j < 128; j++){
        float w = owt[j * 128 + t];
        #pragma unroll
        for (int r = 0; r < 8; r++) acc[r] = fmaf(vp[r][j], w, acc[r]);
    }
    #pragma unroll
    for (int r = 0; r < 8; r++)
        xs[((size_t)(b * 256 + l0 + r)) * 128 + t] += acc[r];
}

// ---------- fused spectral attention: QK+softmax+AV+SO+residual+unsort ----------
__global__ __launch_bounds__(256) void k_spe_attn(const float* __restrict__ q2,
        const float* __restrict__ k2t, const float* __restrict__ v2,
        const float* __restrict__ sowt, const float* __restrict__ sob,
        const float* __restrict__ xs, const int* __restrict__ sidx,
        float* __restrict__ xr){
    __shared__ float qs[8][256];
    __shared__ float lgp[2][8][128];
    __shared__ float sa[8][132];
    __shared__ float av[8][256];
    __shared__ float mxs[8], sms[8];
    int blk = blockIdx.x; int b = blk >> 4; int i0 = (blk & 15) << 3;
    int t = threadIdx.x;
    for (int idx = t; idx < 2048; idx += 256){
        int ii = idx >> 8, d = idx & 255;
        qs[ii][d] = q2[((size_t)(b * 128 + i0 + ii)) * 256 + d];
    }
    __syncthreads();
    {
        int j = t & 127, dh = t >> 7;
        const float* kt = k2t + (size_t)b * 32768 + dh * 16384;
        float acc[8] = {};
        for (int dd = 0; dd < 128; dd++){
            float kv = kt[dd * 128 + j];
            int d = dh * 128 + dd;
            #pragma unroll
            for (int ii = 0; ii < 8; ii++) acc[ii] = fmaf(qs[ii][d], kv, acc[ii]);
        }
        #pragma unroll
        for (int ii = 0; ii < 8; ii++) lgp[dh][ii][j] = acc[ii];
    }
    __syncthreads();
    if (t < 128){
        #pragma unroll
        for (int ii = 0; ii < 8; ii++)
            sa[ii][t] = (lgp[0][ii][t] + lgp[1][ii][t]) * (1.f / 16.f);
    }
    __syncthreads();
    if (t < 8){
        float mx = -3.4e38f;
        for (int j = 0; j < 128; j++) mx = fmaxf(mx, sa[t][j]);
        float sm = 0.f;
        for (int j = 0; j < 128; j++) sm += __expf(sa[t][j] - mx);
        mxs[t] = mx; sms[t] = 1.f / sm;
    }
    __syncthreads();
    if (t < 128){
        #pragma unroll
        for (int ii = 0; ii < 8; ii++)
            sa[ii][t] = __expf(sa[ii][t] - mxs[ii]) * sms[ii];
    }
    __syncthreads();
    {
        float acc[8] = {};
        const float* vb = v2 + (size_t)b * 32768 + t;
        for (int j = 0; j < 128; j++){
            float vv = vb[(size_t)j * 256];
            #pragma unroll
            for (int ii = 0; ii < 8; ii++) acc[ii] = fmaf(sa[ii][j], vv, acc[ii]);
        }
        #pragma unroll
        for (int ii = 0; ii < 8; ii++) av[ii][t] = acc[ii];
    }
    __syncthreads();
    float acc[8] = {};
    for (int d = 0; d < 256; d++){
        float wv = sowt[d * 256 + t];
        #pragma unroll
        for (int ii = 0; ii < 8; ii++) acc[ii] = fmaf(av[ii][d], wv, acc[ii]);
    }
    float bias = sob[t];
    int p = sidx[b * 256 + t];
    const float* xin = xs + ((size_t)(b * 256 + t)) * 128 + i0;
    float* xout = xr + ((size_t)(b * 256 + p)) * 128 + i0;
    #pragma unroll
    for (int ii = 0; ii < 8; ii++) xout[ii] = xin[ii] + acc[ii] + bias;
}

// ---------- conv GEMM split-K=4 with fused im2col (pipelined, fp32) ----------
__global__ __launch_bounds__(256) void k_conv_gemm(const float* __restrict__ xr,
                                                   const float* __restrict__ W2,
                                                   float* __restrict__ part){
    __shared__ float As[16][68];
    __shared__ float Ws[16][64];
    int j0 = blockIdx.x * 64, r0 = blockIdx.y * 64, s = blockIdx.z;
    int tid = threadIdx.x;
    int cg = tid & 15, rg = tid >> 4;
    int arow = tid >> 2, akg = tid & 3;
    int wkk = tid >> 4, wseg = tid & 15;
    int r = r0 + arow; int b = r >> 6, oh = (r >> 3) & 7, ow = r & 7;
    float acc[4][4] = {};
    int kbeg = s * 288, kend = kbeg + 288;
    float4 a4, w4;
    {
        int k = kbeg + akg * 4;
        int khw = k >> 7, c = k & 127;
        int kh = khw / 3, kw = khw - kh * 3;
        int ih = oh * 2 - 1 + kh, iw = ow * 2 - 1 + kw;
        a4 = make_float4(0.f, 0.f, 0.f, 0.f);
        if (ih >= 0 && ih < 16 && iw >= 0 && iw < 16)
            a4 = *(const float4*)(xr + ((size_t)((b << 8) + (ih << 4) + iw)) * 128 + c);
        w4 = *(const float4*)(W2 + (size_t)(kbeg + wkk) * 128 + j0 + wseg * 4);
    }
    for (int k0 = kbeg; k0 < kend; k0 += 16){
        __syncthreads();
        As[akg * 4 + 0][arow] = a4.x; As[akg * 4 + 1][arow] = a4.y;
        As[akg * 4 + 2][arow] = a4.z; As[akg * 4 + 3][arow] = a4.w;
        Ws[wkk][wseg * 4 + 0] = w4.x; Ws[wkk][wseg * 4 + 1] = w4.y;
        Ws[wkk][wseg * 4 + 2] = w4.z; Ws[wkk][wseg * 4 + 3] = w4.w;
        __syncthreads();
        bool more = (k0 + 16 < kend);
        float4 na4, nw4;
        if (more){
            int k = k0 + 16 + akg * 4;
            int khw = k >> 7, c = k & 127;
            int kh = khw / 3, kw = khw - kh * 3;
            int ih = oh * 2 - 1 + kh, iw = ow * 2 - 1 + kw;
            na4 = make_float4(0.f, 0.f, 0.f, 0.f);
            if (ih >= 0 && ih < 16 && iw >= 0 && iw < 16)
                na4 = *(const float4*)(xr + ((size_t)((b << 8) + (ih << 4) + iw)) * 128 + c);
            nw4 = *(const float4*)(W2 + (size_t)(k0 + 16 + wkk) * 128 + j0 + wseg * 4);
        }
        #pragma unroll
        for (int kk = 0; kk < 16; kk++){
            float4 av4 = *(const float4*)(&As[kk][rg << 2]);
            float4 wv4 = *(const float4*)(&Ws[kk][cg << 2]);
            float av_[4] = {av4.x, av4.y, av4.z, av4.w};
            float wv_[4] = {wv4.x, wv4.y, wv4.z, wv4.w};
            #pragma unroll
            for (int ri = 0; ri < 4; ri++)
                #pragma unroll
                for (int ci = 0; ci < 4; ci++)
                    acc[ri][ci] = fmaf(av_[ri], wv_[ci], acc[ri][ci]);
        }
        if (more){ a4 = na4; w4 = nw4; }
    }
    float* pp = part + (size_t)s * 1024 * 128;
    #pragma unroll
    for (int ri = 0; ri < 4; ri++){
        int rr = r0 + (rg << 2) + ri;
        #pragma unroll
        for (int ci = 0; ci < 4; ci++){
            int j = j0 + (cg << 2) + ci;
            pp[(size_t)rr * 128 + j] = acc[ri][ci];
        }
    }
}

// ---------- reduce split-K partials + LayerNorm ----------
__global__ void k_part_ln(const float* __restrict__ part, const float* __restrict__ lnw,
                          const float* __restrict__ lnb, float* __restrict__ out){
    __shared__ float sm[16];
    int r = blockIdx.x, t = threadIdx.x; // 128 thr
    float v = part[(size_t)r * 128 + t]
            + part[(size_t)(1024 + r) * 128 + t]
            + part[(size_t)(2048 + r) * 128 + t]
            + part[(size_t)(3072 + r) * 128 + t];
    float a = v, q = v * v;
    blk_sum2(a, q, sm);
    float mu = a * (1.f / 128.f);
    float var = q * (1.f / 128.f) - mu * mu;
    float rs = rsqrtf(var + 1e-5f);
    out[(size_t)r * 128 + t] = (v - mu) * rs * lnw[t] + lnb[t];
}

extern "C" void kernel_launch(void* const* d_in, const int* in_sizes, int n_in,
                              void* d_out, int out_size, void* d_ws, size_t ws_size,
                              hipStream_t stream) {
    const float* x          = (const float*)d_in[0];
    const int*   sidx       = (const int*)  d_in[1];
    const float* spa_ln_w   = (const float*)d_in[2];
    const float* spa_ln_b   = (const float*)d_in[3];
    const float* spa_in_w   = (const float*)d_in[4];
    const float* spa_conv_w = (const float*)d_in[5];
    const float* spa_conv_b = (const float*)d_in[6];
    const float* spa_dt_bias= (const float*)d_in[7];
    const float* spa_A_log  = (const float*)d_in[8];
    const float* spa_D      = (const float*)d_in[9];
    const float* spa_rms_w  = (const float*)d_in[10];
    const float* spa_out_w  = (const float*)d_in[11];
    const float* spe_ln_w   = (const float*)d_in[12];
    const float* spe_ln_b   = (const float*)d_in[13];
    const float* spe_in_w   = (const float*)d_in[14];
    const float* spe_conv_w = (const float*)d_in[15];
    const float* spe_conv_b = (const float*)d_in[16];
    const float* spe_dt_bias= (const float*)d_in[17];
    const float* spe_A_log  = (const float*)d_in[18];
    const float* spe_D      = (const float*)d_in[19];
    const float* spe_rms_w  = (const float*)d_in[20];
    const float* spe_out_w  = (const float*)d_in[21];
    const float* norm_w     = (const float*)d_in[22];
    const float* norm_b     = (const float*)d_in[23];
    const float* cprj_w     = (const float*)d_in[24];
    const float* cprj_b     = (const float*)d_in[25];
    const float* aq_w       = (const float*)d_in[26];
    const float* aq_b       = (const float*)d_in[27];
    const float* ak_w       = (const float*)d_in[28];
    const float* ak_b       = (const float*)d_in[29];
    const float* av_w       = (const float*)d_in[30];
    const float* av_b       = (const float*)d_in[31];
    const float* ao_w       = (const float*)d_in[32];
    const float* ao_b       = (const float*)d_in[33];
    const float* sq_w       = (const float*)d_in[34];
    const float* sq_b       = (const float*)d_in[35];
    const float* sk_w       = (const float*)d_in[36];
    const float* sk_b       = (const float*)d_in[37];
    const float* sv_w       = (const float*)d_in[38];
    const float* sv_b       = (const float*)d_in[39];
    const float* so_w       = (const float*)d_in[40];
    const float* so_b       = (const float*)d_in[41];
    const float* ds_conv_w  = (const float*)d_in[42];
    const float* ds_ln_w    = (const float*)d_in[43];
    const float* ds_ln_b    = (const float*)d_in[44];

    float* ws = (float*)d_ws;
    // loop-live arena: 0 .. 7946240
    float* xs   = ws + 0;        // 524288
    float* zx   = ws + 1048576;  // -> 3686400
    float* xc   = ws + 3686400;  // -> 5259264
    float* dtb  = ws + 5259264;  // 32768
    float* dAb  = ws + 5292032;  // 32768 (log-dA)
    float* yb   = ws + 5324800;  // -> 6373376
    float* Sbuf = ws + 6373376;  // -> 7421952
    float* h1   = ws + 7421952;  // -> 7946240
    float* clbuf = ws + 524288;  // scratch (dead between uses)
    float* xT    = ws + 524288;  // scratch (dead after k_embed)
    // h1t aliases Sbuf: written by spatial gemm_gate (mode 4) AFTER chunk_y's
    // last S read, consumed by spectral gemm_ln BEFORE spectral ssd_chunk
    // rewrites Sbuf.
    float* h1t   = ws + 6373376;
    // weight transposes: PAST the loop-live arena
    float* owt   = ws + 7946240; // 16384 -> 7962624
    float* sowt  = ws + 7962624; // 65536 -> 8028160
    // attention-stage aliases (host regions dead post-loop)
    float* kb    = ws + 1048576;
    float* vb    = ws + 1572864;
    float* attnb = ws + 2097152;
    float* qb    = ws + 2129920;
    float* xt    = ws + 524288;
    float* q2    = ws + 3686400;
    float* k2t   = ws + 4210688;
    float* v2    = ws + 4734976;
    float* xr    = ws + 5586944; // -> 6111232
    float* part  = ws + 1048576; // kb/vb region, dead by conv_gemm

    k_tr_multi<<<592, 256, 0, stream>>>(x, xT, ao_w, owt, so_w, sowt);
    k_embed<<<4096, 128, 0, stream>>>(xT, sidx, xs);

    for (int i = 0; i < 2; i++){
        // ---- spatial mamba (L=256, nh=4, nc=4) ----
        k_gemm_ln<<<dim3(11, 64), 256, 0, stream>>>(xs, spa_in_w + (size_t)i * 644 * 128,
                                                    spa_ln_w + i * 128, spa_ln_b + i * 128,
                                                    zx, 644, 128);
        k_conv<<<4096, 256, 0, stream>>>(zx, spa_conv_w + (size_t)i * 384 * 4,
                                         spa_conv_b + i * 384, xc,
                                         spa_dt_bias + i * 4, spa_A_log + i * 4, dtb, dAb,
                                         256, 384, 644, 256, 4, 640);
        k_ssd_chunk<<<256, 256, 0, stream>>>(xc, dtb, dAb, yb, Sbuf, clbuf,
                                             256, 4, 4, 384, 256, 320, 256);
        k_chunk_y<<<256, 256, 0, stream>>>(xc, Sbuf, clbuf, spa_D + i * 4, yb,
                                           256, 4, 4, 384, 320, 256);
        k_gemm_gate<<<dim3(2, 64), 256, 0, stream>>>(yb, zx, spa_rms_w + i * 256,
                                                     spa_out_w + (size_t)i * 128 * 256,
                                                     xs, h1, h1t, 128, 256, 644, 4);
        // ---- spectral mamba (L=128, nh=8, nc=2) ----
        k_gemm_ln<<<dim3(19, 32), 256, 0, stream>>>(h1t, spe_in_w + (size_t)i * 1160 * 256,
                                                    spe_ln_w + i * 256, spe_ln_b + i * 256,
                                                    zx, 1160, 256);
        k_conv<<<2048, 256, 0, stream>>>(zx, spe_conv_w + (size_t)i * 640 * 4,
                                         spe_conv_b + i * 640, xc,
                                         spe_dt_bias + i * 8, spe_A_log + i * 8, dtb, dAb,
                                         128, 640, 1160, 512, 8, 1152);
        k_ssd_chunk<<<256, 256, 0, stream>>>(xc, dtb, dAb, yb, Sbuf, clbuf,
                                             128, 8, 2, 640, 512, 576, 512);
        k_chunk_y<<<256, 256, 0, stream>>>(xc, Sbuf, clbuf, spe_D + i * 8, yb,
                                           128, 8, 2, 640, 576, 512);
        k_gemm_gate<<<dim3(4, 32), 256, 0, stream>>>(yb, zx, spe_rms_w + i * 512,
                                                     spe_out_w + (size_t)i * 256 * 512,
                                                     h1, xs, nullptr, 256, 512, 1160, 2);
    }

    k_ln<<<4096, 128, 0, stream>>>(xs, norm_w, norm_b, xs, 128);
    k_center_q<<<16, 128, 0, stream>>>(xs, cprj_w, cprj_b, aq_w, aq_b, qb);
    {
        GJob jk = {ak_w, ak_b, kb, 0};
        GJob jv = {av_w, av_b, vb, 0};
        k_gemm3<<<dim3(2, 64, 2), 256, 0, stream>>>(xs, jk, jv, jk, 128, 128);
    }
    k_attn<<<128, 256, 0, stream>>>(qb, kb, attnb);
    k_attn_out<<<512, 128, 0, stream>>>(vb, attnb, owt, ao_b, xs);
    k_tr<<<dim3(4, 8, 16), 256, 0, stream>>>(xs, xt, 256, 128);
    {
        GJob jq = {sq_w, sq_b, q2, 0};
        GJob jk = {sk_w, sk_b, k2t, 3};
        GJob jv = {sv_w, sv_b, v2, 0};
        k_gemm3<<<dim3(4, 32, 3), 256, 0, stream>>>(xt, jq, jk, jv, 256, 256);
    }
    k_spe_attn<<<256, 256, 0, stream>>>(q2, k2t, v2, sowt, so_b, xs, sidx, xr);
    k_conv_gemm<<<dim3(2, 16, 4), 256, 0, stream>>>(xr, ds_conv_w, part);
    k_part_ln<<<1024, 128, 0, stream>>>(part, ds_ln_w, ds_ln_b, (float*)d_out);
}

// Round 16
// 526.052 us; speedup vs baseline: 1.1695x; 1.0492x over previous
//
#include <hip/hip_runtime.h>
#include <math.h>

#define DEV __device__ __forceinline__

typedef __attribute__((ext_vector_type(8))) short short8;
typedef __attribute__((ext_vector_type(4))) float f32x4;
typedef unsigned short ushort_t;
typedef unsigned int uint_t;

DEV float siluf(float x){ return x / (1.f + __expf(-x)); }
DEV float softplusf(float x){ return (x > 20.f) ? x : log1pf(__expf(x)); }

DEV ushort_t bf16r(float f){
    uint_t u = __float_as_uint(f);
    return (ushort_t)((u + 0x7fffu + ((u >> 16) & 1u)) >> 16);
}
DEV uint_t pack2(float a, float b){
    return (uint_t)bf16r(a) | ((uint_t)bf16r(b) << 16);
}

// ---------- block reduction helpers (wave64) ----------
DEV void blk_sum2(float &a, float &b, float* sm){
    int lane = threadIdx.x & 63, wid = threadIdx.x >> 6, nw = blockDim.x >> 6;
    #pragma unroll
    for (int off = 32; off; off >>= 1){ a += __shfl_down(a, off); b += __shfl_down(b, off); }
    if (lane == 0){ sm[wid] = a; sm[8 + wid] = b; }
    __syncthreads();
    float ra = 0.f, rb = 0.f;
    for (int i = 0; i < nw; i++){ ra += sm[i]; rb += sm[8 + i]; }
    __syncthreads();
    a = ra; b = rb;
}
DEV float blk_sum1(float v, float* sm){
    int lane = threadIdx.x & 63, wid = threadIdx.x >> 6, nw = blockDim.x >> 6;
    #pragma unroll
    for (int off = 32; off; off >>= 1) v += __shfl_down(v, off);
    if (lane == 0) sm[wid] = v;
    __syncthreads();
    float r = 0.f;
    for (int i = 0; i < nw; i++) r += sm[i];
    __syncthreads();
    return r;
}
DEV float blk_max1(float v, float* sm){
    int lane = threadIdx.x & 63, wid = threadIdx.x >> 6, nw = blockDim.x >> 6;
    #pragma unroll
    for (int off = 32; off; off >>= 1) v = fmaxf(v, __shfl_down(v, off));
    if (lane == 0) sm[wid] = v;
    __syncthreads();
    float r = -3.4e38f;
    for (int i = 0; i < nw; i++) r = fmaxf(r, sm[i]);
    __syncthreads();
    return r;
}

// ---------- transpose body ----------
DEV void tr_body(const float* __restrict__ ip, float* __restrict__ op,
                 int R, int C, int c0, int r0){
    __shared__ float tile[32][33];
    int tx = threadIdx.x & 31, ty = threadIdx.x >> 5;
    #pragma unroll
    for (int rr = ty; rr < 32; rr += 8)
        tile[rr][tx] = ip[(size_t)(r0 + rr) * C + c0 + tx];
    __syncthreads();
    #pragma unroll
    for (int rr = ty; rr < 32; rr += 8)
        op[(size_t)(c0 + rr) * R + r0 + tx] = tile[tx][rr];
}

__global__ __launch_bounds__(256) void k_tr(const float* __restrict__ in,
                                            float* __restrict__ out, int R, int C){
    tr_body(in + (size_t)blockIdx.z * R * C, out + (size_t)blockIdx.z * R * C,
            R, C, blockIdx.x * 32, blockIdx.y * 32);
}

// packed: job0 x->xT (512 blks), job1 ao_w (16), job2 so_w (64)
__global__ __launch_bounds__(256) void k_tr_multi(const float* __restrict__ x,
        float* __restrict__ xT, const float* __restrict__ aow, float* __restrict__ owt,
        const float* __restrict__ sow, float* __restrict__ sowt){
    int idx = blockIdx.x;
    if (idx < 512){
        int bx = idx & 7, by = (idx >> 3) & 3, bz = idx >> 5;
        tr_body(x + (size_t)bz * 32768, xT + (size_t)bz * 32768, 128, 256, bx * 32, by * 32);
    } else if (idx < 528){
        int l = idx - 512;
        tr_body(aow, owt, 128, 128, (l & 3) * 32, (l >> 2) * 32);
    } else {
        int l = idx - 528;
        tr_body(sow, sowt, 256, 256, (l & 7) * 32, (l >> 3) * 32);
    }
}

// ---------- K1: pos-embed + gather ----------
__global__ void k_embed(const float* __restrict__ xT, const int* __restrict__ sidx,
                        float* __restrict__ xs){
    int bl = blockIdx.x; int b = bl >> 8; int c = threadIdx.x;
    int p = sidx[bl];
    int hh = p >> 4, ww = p & 15;
    int pos = (c < 64) ? hh : ww;
    int jm = c & 63;
    float om = __expf(-(float)(jm & 31) * 0.28782313662425574f); // ln(10000)/32
    float ang = (float)pos * om;
    float pe = (jm < 32) ? sinf(ang) : cosf(ang);
    xs[(size_t)bl * 128 + c] = xT[((size_t)(b * 256 + p)) * 128 + c] + pe;
}

// ---------- LayerNorm (block per row) ----------
__global__ void k_ln(const float* __restrict__ in, const float* __restrict__ w,
                     const float* __restrict__ bb, float* __restrict__ out, int dim){
    __shared__ float sm[16];
    int row = blockIdx.x, t = threadIdx.x;
    float v = in[(size_t)row * dim + t];
    float a = v, q = v * v;
    blk_sum2(a, q, sm);
    float inv = 1.f / (float)dim;
    float mu = a * inv;
    float var = q * inv - mu * mu;
    float rs = rsqrtf(var + 1e-5f);
    out[(size_t)row * dim + t] = (v - mu) * rs * w[t] + bb[t];
}

// ======================================================================
// bf16 MFMA GEMM family.
// 64-row kernels (gemm_ln): 64x64 tile, 4 waves x 16-row stripes.
// 32-row kernels (gate/qkv): 32x64 tile, 4 waves = 2 row-stripes x 2 col-pairs.
// A/B frag: elem [lane&15][quad*8+j]; C/D: col=lane&15, row=quad*4+reg.
// ======================================================================

// ---------- in-projection GEMM with fused LayerNorm (bf16 MFMA, 64-row) ----------
__global__ __launch_bounds__(256) void k_gemm_ln(const float* __restrict__ A,
        const float* __restrict__ W, const float* __restrict__ lw,
        const float* __restrict__ lb, float* __restrict__ out, int N, int K){
    __shared__ __align__(16) ushort_t smem[2 * 64 * 72];
    ushort_t (*Abf)[72] = (ushort_t (*)[72])smem;
    ushort_t (*Wbf)[72] = (ushort_t (*)[72])(smem + 64 * 72);
    int j0 = blockIdx.x * 64, r0 = blockIdx.y * 64;
    int tid = threadIdx.x;
    int row = tid >> 2, kg = tid & 3;
    int wrow = j0 + row; if (wrow > N - 1) wrow = N - 1;
    const float* Ar = A + (size_t)(r0 + row) * K;
    const float* Wr = W + (size_t)wrow * K;
    float s = 0.f, ss = 0.f;
    for (int k0 = 0; k0 < K; k0 += 32){
        float4 a0 = *(const float4*)(Ar + k0 + kg * 4);
        float4 a1 = *(const float4*)(Ar + k0 + 16 + kg * 4);
        s  += a0.x + a0.y + a0.z + a0.w + a1.x + a1.y + a1.z + a1.w;
        ss += a0.x*a0.x + a0.y*a0.y + a0.z*a0.z + a0.w*a0.w
            + a1.x*a1.x + a1.y*a1.y + a1.z*a1.z + a1.w*a1.w;
    }
    s  += __shfl_xor(s, 1);  ss += __shfl_xor(ss, 1);
    s  += __shfl_xor(s, 2);  ss += __shfl_xor(ss, 2);
    float inv = 1.f / (float)K;
    float mu = s * inv;
    float rs = rsqrtf(ss * inv - mu * mu + 1e-5f);
    int wv = tid >> 6, lane = tid & 63, lm = lane & 15, quad = lane >> 4;
    f32x4 zero4 = {0.f, 0.f, 0.f, 0.f};
    f32x4 acc[4] = {zero4, zero4, zero4, zero4};
    for (int kc0 = 0; kc0 < K; kc0 += 64){
        int kb = kc0 + kg * 16;
        float4 q[4], g[4], b[4], p[4];
        #pragma unroll
        for (int i = 0; i < 4; i++){
            q[i] = *(const float4*)(Ar + kb + i * 4);
            g[i] = *(const float4*)(lw + kb + i * 4);
            b[i] = *(const float4*)(lb + kb + i * 4);
            p[i] = *(const float4*)(Wr + kb + i * 4);
        }
        #pragma unroll
        for (int i = 0; i < 4; i++){
            q[i].x = (q[i].x - mu) * rs * g[i].x + b[i].x;
            q[i].y = (q[i].y - mu) * rs * g[i].y + b[i].y;
            q[i].z = (q[i].z - mu) * rs * g[i].z + b[i].z;
            q[i].w = (q[i].w - mu) * rs * g[i].w + b[i].w;
        }
        __syncthreads();
        {
            uint4 u0, u1;
            u0.x = pack2(q[0].x, q[0].y); u0.y = pack2(q[0].z, q[0].w);
            u0.z = pack2(q[1].x, q[1].y); u0.w = pack2(q[1].z, q[1].w);
            u1.x = pack2(q[2].x, q[2].y); u1.y = pack2(q[2].z, q[2].w);
            u1.z = pack2(q[3].x, q[3].y); u1.w = pack2(q[3].z, q[3].w);
            *(uint4*)&Abf[row][kg * 16] = u0;
            *(uint4*)&Abf[row][kg * 16 + 8] = u1;
            u0.x = pack2(p[0].x, p[0].y); u0.y = pack2(p[0].z, p[0].w);
            u0.z = pack2(p[1].x, p[1].y); u0.w = pack2(p[1].z, p[1].w);
            u1.x = pack2(p[2].x, p[2].y); u1.y = pack2(p[2].z, p[2].w);
            u1.z = pack2(p[3].x, p[3].y); u1.w = pack2(p[3].z, p[3].w);
            *(uint4*)&Wbf[row][kg * 16] = u0;
            *(uint4*)&Wbf[row][kg * 16 + 8] = u1;
        }
        __syncthreads();
        #pragma unroll
        for (int kk = 0; kk < 64; kk += 32){
            short8 af = *(const short8*)&Abf[wv * 16 + lm][kk + quad * 8];
            #pragma unroll
            for (int c = 0; c < 4; c++){
                short8 bfv = *(const short8*)&Wbf[c * 16 + lm][kk + quad * 8];
                acc[c] = __builtin_amdgcn_mfma_f32_16x16x32_bf16(af, bfv, acc[c], 0, 0, 0);
            }
        }
    }
    int rbase = r0 + wv * 16 + quad * 4;
    #pragma unroll
    for (int c = 0; c < 4; c++){
        int j = j0 + c * 16 + lm;
        if (j < N){
            #pragma unroll
            for (int reg = 0; reg < 4; reg++)
                out[(size_t)(rbase + reg) * N + j] = acc[c][reg];
        }
    }
}

// ---------- out-projection GEMM, fused gate(silu)+RMS (bf16 MFMA, 32-row) ----------
// grid (N/64, M/32). mode 1: out = .*scale + res
// mode 2: transposed scatter (N==256): out[((r0>>7)*256+j)*128+(r&127)] = . + res
// mode 4: mode 1 + ALSO out2 transposed: out2[((r0>>8)*128+j)*256+(r&255)] = same
__global__ __launch_bounds__(256) void k_gemm_gate(const float* __restrict__ Y,
        const float* __restrict__ Z, const float* __restrict__ rw,
        const float* __restrict__ W, const float* __restrict__ res,
        float* __restrict__ out, float* __restrict__ out2,
        int N, int K, int zs, int mode){
    __shared__ __align__(16) ushort_t smem[96 * 72]; // Wbf[64][72] then Abf[32][72]
    ushort_t (*Wbf)[72] = (ushort_t (*)[72])smem;
    ushort_t (*Abf)[72] = (ushort_t (*)[72])(smem + 64 * 72);
    __shared__ float sscale[32];
    int j0 = blockIdx.x * 64, r0 = blockIdx.y * 32;
    int tid = threadIdx.x;
    int arow = tid >> 3, kseg = tid & 7;   // A staging: 32 rows x 8 lanes
    int wrow_ = tid >> 2, wkg = tid & 3;   // W staging: 64 rows x 4 lanes
    const float* Yr = Y + (size_t)(r0 + arow) * K + kseg * 8;
    const float* Zr = Z + (size_t)(r0 + arow) * zs + kseg * 8;
    const float* Gr = rw + kseg * 8;
    const float* Wr = W + (size_t)(j0 + wrow_) * K + wkg * 16;
    int wv = tid >> 6, lane = tid & 63, lm = lane & 15, quad = lane >> 4;
    int rs = wv & 1, cp = wv >> 1;
    float ssq = 0.f;
    f32x4 zero4 = {0.f, 0.f, 0.f, 0.f};
    f32x4 acc[2] = {zero4, zero4};
    for (int kc0 = 0; kc0 < K; kc0 += 64){
        float4 y[2], z[2], g[2], p[4];
        y[0] = *(const float4*)(Yr + kc0);  y[1] = *(const float4*)(Yr + kc0 + 4);
        z[0] = *(const float4*)(Zr + kc0);  z[1] = *(const float4*)(Zr + kc0 + 4);
        g[0] = *(const float4*)(Gr + kc0);  g[1] = *(const float4*)(Gr + kc0 + 4);
        #pragma unroll
        for (int i = 0; i < 4; i++) p[i] = *(const float4*)(Wr + kc0 + i * 4);
        #pragma unroll
        for (int i = 0; i < 2; i++){
            y[i].x *= siluf(z[i].x); y[i].y *= siluf(z[i].y);
            y[i].z *= siluf(z[i].z); y[i].w *= siluf(z[i].w);
            ssq += y[i].x*y[i].x + y[i].y*y[i].y + y[i].z*y[i].z + y[i].w*y[i].w;
            y[i].x *= g[i].x; y[i].y *= g[i].y; y[i].z *= g[i].z; y[i].w *= g[i].w;
        }
        __syncthreads();
        {
            uint4 ua;
            ua.x = pack2(y[0].x, y[0].y); ua.y = pack2(y[0].z, y[0].w);
            ua.z = pack2(y[1].x, y[1].y); ua.w = pack2(y[1].z, y[1].w);
            *(uint4*)&Abf[arow][kseg * 8] = ua;
            uint4 u0, u1;
            u0.x = pack2(p[0].x, p[0].y); u0.y = pack2(p[0].z, p[0].w);
            u0.z = pack2(p[1].x, p[1].y); u0.w = pack2(p[1].z, p[1].w);
            u1.x = pack2(p[2].x, p[2].y); u1.y = pack2(p[2].z, p[2].w);
            u1.z = pack2(p[3].x, p[3].y); u1.w = pack2(p[3].z, p[3].w);
            *(uint4*)&Wbf[wrow_][wkg * 16] = u0;
            *(uint4*)&Wbf[wrow_][wkg * 16 + 8] = u1;
        }
        __syncthreads();
        #pragma unroll
        for (int kk = 0; kk < 64; kk += 32){
            short8 af = *(const short8*)&Abf[rs * 16 + lm][kk + quad * 8];
            #pragma unroll
            for (int c = 0; c < 2; c++){
                short8 bfv = *(const short8*)&Wbf[(cp * 2 + c) * 16 + lm][kk + quad * 8];
                acc[c] = __builtin_amdgcn_mfma_f32_16x16x32_bf16(af, bfv, acc[c], 0, 0, 0);
            }
        }
    }
    ssq += __shfl_xor(ssq, 1);
    ssq += __shfl_xor(ssq, 2);
    ssq += __shfl_xor(ssq, 4);
    if (kseg == 0) sscale[arow] = rsqrtf(ssq / (float)K + 1e-5f);
    __syncthreads(); // sscale visible; all LDS fragment reads done
    int lr0 = rs * 16 + quad * 4;
    float scr[4];
    #pragma unroll
    for (int reg = 0; reg < 4; reg++) scr[reg] = sscale[lr0 + reg];
    if (mode == 2){
        float (*T)[36] = (float (*)[36])smem; // 64x36x4 = 9216 B <= 13824 B
        #pragma unroll
        for (int c = 0; c < 2; c++)
            #pragma unroll
            for (int reg = 0; reg < 4; reg++)
                T[(cp * 2 + c) * 16 + lm][lr0 + reg] = acc[c][reg] * scr[reg];
        __syncthreads();
        int b2 = r0 >> 7, ii0 = r0 & 127;
        int jj = tid >> 2, seg = tid & 3;
        size_t base = ((size_t)(b2 * 256 + j0 + jj)) * 128 + ii0 + seg * 8;
        float* op = out + base;
        const float* rp = res + base;
        #pragma unroll
        for (int cc = 0; cc < 2; cc++){
            float4 v = make_float4(T[jj][seg * 8 + cc * 4 + 0], T[jj][seg * 8 + cc * 4 + 1],
                                   T[jj][seg * 8 + cc * 4 + 2], T[jj][seg * 8 + cc * 4 + 3]);
            float4 rv = *(const float4*)(rp + cc * 4);
            v.x += rv.x; v.y += rv.y; v.z += rv.z; v.w += rv.w;
            *(float4*)(op + cc * 4) = v;
        }
    } else { // mode 1 or 4
        float (*T)[36] = (float (*)[36])smem;
        int rbase = r0 + lr0;
        #pragma unroll
        for (int c = 0; c < 2; c++){
            int j = j0 + (cp * 2 + c) * 16 + lm;
            #pragma unroll
            for (int reg = 0; reg < 4; reg++){
                size_t oi = (size_t)(rbase + reg) * N + j;
                float v = acc[c][reg] * scr[reg] + res[oi];
                out[oi] = v;
                if (mode == 4) T[(cp * 2 + c) * 16 + lm][lr0 + reg] = v;
            }
        }
        if (mode == 4){
            __syncthreads();
            int bb = r0 >> 8, lbase = r0 & 255;
            int jj = tid >> 2, seg = tid & 3;
            size_t base2 = ((size_t)(bb * 128 + j0 + jj)) * 256 + lbase + seg * 8;
            float* op = out2 + base2;
            #pragma unroll
            for (int cc = 0; cc < 2; cc++){
                float4 v = make_float4(T[jj][seg * 8 + cc * 4 + 0], T[jj][seg * 8 + cc * 4 + 1],
                                       T[jj][seg * 8 + cc * 4 + 2], T[jj][seg * 8 + cc * 4 + 3]);
                *(float4*)(op + cc * 4) = v;
            }
        }
    }
}

// ---------- qkv GEMM (bf16 MFMA, 32-row), mode 0: +bias; mode 3: transposed+bias ----------
struct GJob { const float* W; const float* bias; float* out; int mode; };

__global__ __launch_bounds__(256) void k_gemm3(const float* __restrict__ A,
                                               GJob ja, GJob jb, GJob jc,
                                               int N, int K){
    GJob job = (blockIdx.z == 0) ? ja : ((blockIdx.z == 1) ? jb : jc);
    const float* W = job.W;
    const float* bias = job.bias;
    float* out = job.out;
    int mode = job.mode;
    __shared__ __align__(16) ushort_t smem[96 * 72];
    ushort_t (*Wbf)[72] = (ushort_t (*)[72])smem;
    ushort_t (*Abf)[72] = (ushort_t (*)[72])(smem + 64 * 72);
    int j0 = blockIdx.x * 64, r0 = blockIdx.y * 32;
    int tid = threadIdx.x;
    int arow = tid >> 3, kseg = tid & 7;
    int wrow_ = tid >> 2, wkg = tid & 3;
    const float* Ar = A + (size_t)(r0 + arow) * K + kseg * 8;
    const float* Wr = W + (size_t)(j0 + wrow_) * K + wkg * 16;
    int wv = tid >> 6, lane = tid & 63, lm = lane & 15, quad = lane >> 4;
    int rs = wv & 1, cp = wv >> 1;
    f32x4 zero4 = {0.f, 0.f, 0.f, 0.f};
    f32x4 acc[2] = {zero4, zero4};
    for (int kc0 = 0; kc0 < K; kc0 += 64){
        float4 q[2], p[4];
        q[0] = *(const float4*)(Ar + kc0);  q[1] = *(const float4*)(Ar + kc0 + 4);
        #pragma unroll
        for (int i = 0; i < 4; i++) p[i] = *(const float4*)(Wr + kc0 + i * 4);
        __syncthreads();
        {
            uint4 ua;
            ua.x = pack2(q[0].x, q[0].y); ua.y = pack2(q[0].z, q[0].w);
            ua.z = pack2(q[1].x, q[1].y); ua.w = pack2(q[1].z, q[1].w);
            *(uint4*)&Abf[arow][kseg * 8] = ua;
            uint4 u0, u1;
            u0.x = pack2(p[0].x, p[0].y); u0.y = pack2(p[0].z, p[0].w);
            u0.z = pack2(p[1].x, p[1].y); u0.w = pack2(p[1].z, p[1].w);
            u1.x = pack2(p[2].x, p[2].y); u1.y = pack2(p[2].z, p[2].w);
            u1.z = pack2(p[3].x, p[3].y); u1.w = pack2(p[3].z, p[3].w);
            *(uint4*)&Wbf[wrow_][wkg * 16] = u0;
            *(uint4*)&Wbf[wrow_][wkg * 16 + 8] = u1;
        }
        __syncthreads();
        #pragma unroll
        for (int kk = 0; kk < 64; kk += 32){
            short8 af = *(const short8*)&Abf[rs * 16 + lm][kk + quad * 8];
            #pragma unroll
            for (int c = 0; c < 2; c++){
                short8 bfv = *(const short8*)&Wbf[(cp * 2 + c) * 16 + lm][kk + quad * 8];
                acc[c] = __builtin_amdgcn_mfma_f32_16x16x32_bf16(af, bfv, acc[c], 0, 0, 0);
            }
        }
    }
    int lr0 = rs * 16 + quad * 4;
    if (mode == 3){
        __syncthreads();
        float (*T)[36] = (float (*)[36])smem;
        #pragma unroll
        for (int c = 0; c < 2; c++)
            #pragma unroll
            for (int reg = 0; reg < 4; reg++)
                T[(cp * 2 + c) * 16 + lm][lr0 + reg] = acc[c][reg];
        __syncthreads();
        int b2 = r0 >> 7, ii0 = r0 & 127;
        int jj = tid >> 2, seg = tid & 3;
        size_t base = ((size_t)(b2 * 256 + j0 + jj)) * 128 + ii0 + seg * 8;
        float* op = out + base;
        float bj = bias[j0 + jj];
        #pragma unroll
        for (int cc = 0; cc < 2; cc++){
            float4 v = make_float4(T[jj][seg * 8 + cc * 4 + 0] + bj,
                                   T[jj][seg * 8 + cc * 4 + 1] + bj,
                                   T[jj][seg * 8 + cc * 4 + 2] + bj,
                                   T[jj][seg * 8 + cc * 4 + 3] + bj);
            *(float4*)(op + cc * 4) = v;
        }
    } else {
        int rbase = r0 + lr0;
        #pragma unroll
        for (int c = 0; c < 2; c++){
            int j = j0 + (cp * 2 + c) * 16 + lm;
            float bj = bias[j];
            #pragma unroll
            for (int reg = 0; reg < 4; reg++)
                out[(size_t)(rbase + reg) * N + j] = acc[c][reg] + bj;
        }
    }
}

// ---------- causal depthwise conv(4)+bias+silu, fused dt / log-dA ----------
__global__ void k_conv(const float* __restrict__ zx, const float* __restrict__ cw,
                       const float* __restrict__ cb, float* __restrict__ xc,
                       const float* __restrict__ dtbias, const float* __restrict__ Al,
                       float* __restrict__ dt, float* __restrict__ dlA,
                       int L, int D, int stride, int off, int nh, int dtoff){
    int bl = blockIdx.x;
    int l = bl & (L - 1);
    const float* base = zx + (size_t)bl * stride + off;
    for (int d = threadIdx.x; d < D; d += blockDim.x){
        float acc = cb[d];
        #pragma unroll
        for (int k = 0; k < 4; k++){
            int dl = l + k - 3;
            if (dl >= 0) acc += base[(ptrdiff_t)(k - 3) * stride + d] * cw[d * 4 + k];
        }
        xc[(size_t)bl * D + d] = siluf(acc);
    }
    int t = threadIdx.x;
    if (t < nh){
        float xv = zx[(size_t)bl * stride + dtoff + t] + dtbias[t];
        float d = softplusf(xv);
        dt[(size_t)bl * nh + t] = d;
        dlA[(size_t)bl * nh + t] = -d * __expf(Al[t]); // log(dA) <= 0
    }
}

// ---------- chunked SSD, stage A ----------
__global__ __launch_bounds__(256) void k_ssd_chunk(
        const float* __restrict__ xc, const float* __restrict__ dt,
        const float* __restrict__ dlA, float* __restrict__ y,
        float* __restrict__ S, float* __restrict__ clb,
        int L, int nh, int nc, int xcs, int bo, int co, int ys){
    __shared__ float sX[64][68];
    __shared__ float sB[64][68];
    __shared__ float sC[64][68]; // phase1: C ; after: masked G
    __shared__ float cl[64], sdt[64], sw[64];
    int blk = blockIdx.x;
    int c = blk % nc; int bh = blk / nc; int h = bh % nh; int b = bh / nh;
    int l0 = c * 64;
    int tid = threadIdx.x;
    const float* base = xc + ((size_t)(b * L + l0)) * xcs;
    for (int idx = tid; idx < 4096; idx += 256){
        int s = idx >> 6, n = idx & 63;
        const float* row = base + (size_t)s * xcs;
        sX[s][n] = row[h * 64 + n];
        sB[s][n] = row[bo + n];
        sC[s][n] = row[co + n];
    }
    if (tid < 64){
        size_t di = (size_t)(b * L + l0 + tid) * nh + h;
        float dlv = dlA[di];
        sdt[tid] = dt[di];
        #pragma unroll
        for (int off = 1; off < 64; off <<= 1){
            float o = __shfl_up(dlv, off, 64);
            if (tid >= off) dlv += o;
        }
        cl[tid] = dlv;
        clb[(size_t)blk * 64 + tid] = dlv;
    }
    __syncthreads();
    if (tid < 64) sw[tid] = __expf(cl[63] - cl[tid]) * sdt[tid];

    int g1 = tid >> 4, g2 = tid & 15;
    int t0 = g1 * 4, s0 = g2 * 4;
    float g[4][4] = {};
    for (int n = 0; n < 64; n += 4){
        float4 cv[4], bv[4];
        #pragma unroll
        for (int i = 0; i < 4; i++) cv[i] = *(const float4*)&sC[t0 + i][n];
        #pragma unroll
        for (int j = 0; j < 4; j++) bv[j] = *(const float4*)&sB[s0 + j][n];
        #pragma unroll
        for (int i = 0; i < 4; i++)
            #pragma unroll
            for (int j = 0; j < 4; j++){
                g[i][j] = fmaf(cv[i].x, bv[j].x, g[i][j]);
                g[i][j] = fmaf(cv[i].y, bv[j].y, g[i][j]);
                g[i][j] = fmaf(cv[i].z, bv[j].z, g[i][j]);
                g[i][j] = fmaf(cv[i].w, bv[j].w, g[i][j]);
            }
    }
    __syncthreads();
    #pragma unroll
    for (int i = 0; i < 4; i++)
        #pragma unroll
        for (int j = 0; j < 4; j++){
            int t = t0 + i, s = s0 + j;
            float v = 0.f;
            if (s <= t) v = g[i][j] * __expf(cl[t] - cl[s]) * sdt[s];
            sC[t][s] = v;
        }
    __syncthreads();
    {
        float acc[4][4] = {};
        for (int s = 0; s < 64; s++){
            float4 xv = *(const float4*)&sX[s][s0];
            float gv[4];
            #pragma unroll
            for (int i = 0; i < 4; i++) gv[i] = sC[t0 + i][s];
            #pragma unroll
            for (int i = 0; i < 4; i++){
                acc[i][0] = fmaf(gv[i], xv.x, acc[i][0]);
                acc[i][1] = fmaf(gv[i], xv.y, acc[i][1]);
                acc[i][2] = fmaf(gv[i], xv.z, acc[i][2]);
                acc[i][3] = fmaf(gv[i], xv.w, acc[i][3]);
            }
        }
        #pragma unroll
        for (int i = 0; i < 4; i++){
            float4 o = make_float4(acc[i][0], acc[i][1], acc[i][2], acc[i][3]);
            *(float4*)&y[(size_t)(b * L + l0 + t0 + i) * ys + h * 64 + s0] = o;
        }
    }
    {
        float acc[4][4] = {};
        int p0 = t0, n0 = s0;
        for (int s = 0; s < 64; s++){
            float wv = sw[s];
            float4 bv = *(const float4*)&sB[s][n0];
            float4 xv = *(const float4*)&sX[s][p0];
            float w0 = wv * xv.x, w1 = wv * xv.y, w2 = wv * xv.z, w3 = wv * xv.w;
            acc[0][0] = fmaf(w0, bv.x, acc[0][0]); acc[0][1] = fmaf(w0, bv.y, acc[0][1]);
            acc[0][2] = fmaf(w0, bv.z, acc[0][2]); acc[0][3] = fmaf(w0, bv.w, acc[0][3]);
            acc[1][0] = fmaf(w1, bv.x, acc[1][0]); acc[1][1] = fmaf(w1, bv.y, acc[1][1]);
            acc[1][2] = fmaf(w1, bv.z, acc[1][2]); acc[1][3] = fmaf(w1, bv.w, acc[1][3]);
            acc[2][0] = fmaf(w2, bv.x, acc[2][0]); acc[2][1] = fmaf(w2, bv.y, acc[2][1]);
            acc[2][2] = fmaf(w2, bv.z, acc[2][2]); acc[2][3] = fmaf(w2, bv.w, acc[2][3]);
            acc[3][0] = fmaf(w3, bv.x, acc[3][0]); acc[3][1] = fmaf(w3, bv.y, acc[3][1]);
            acc[3][2] = fmaf(w3, bv.z, acc[3][2]); acc[3][3] = fmaf(w3, bv.w, acc[3][3]);
        }
        float* Sp = S + (size_t)blk * 4096;
        #pragma unroll
        for (int i = 0; i < 4; i++){
            float4 o = make_float4(acc[i][0], acc[i][1], acc[i][2], acc[i][3]);
            *(float4*)&Sp[(p0 + i) * 64 + n0] = o;
        }
    }
}

// ---------- chunked SSD, stage B+C fused ----------
__global__ __launch_bounds__(256) void k_chunk_y(
        const float* __restrict__ xc, const float* __restrict__ S,
        const float* __restrict__ clb, const float* __restrict__ Dp,
        float* __restrict__ y,
        int L, int nh, int nc, int xcs, int co, int ys){
    __shared__ float sH[64][68];
    __shared__ float sC[64][68];
    __shared__ float scl[64];
    int blk = blockIdx.x;
    int c = blk % nc; int bh = blk / nc; int h = bh % nh; int b = bh / nh;
    int l0 = c * 64;
    int tid = threadIdx.x;
    float wch[4];
    {
        float w = 1.f;
        for (int cp = c - 1; cp >= 0; cp--){
            wch[cp] = w;
            w *= __expf(clb[((size_t)(bh * nc + cp)) * 64 + 63]);
        }
    }
    const float* Sb = S + (size_t)(bh * nc) * 4096;
    const float* base = xc + ((size_t)(b * L + l0)) * xcs;
    for (int idx = tid; idx < 4096; idx += 256){
        int r = idx >> 6, n = idx & 63;
        float hv = 0.f;
        for (int cp = 0; cp < c; cp++)
            hv = fmaf(wch[cp], Sb[(size_t)cp * 4096 + idx], hv);
        sH[r][n] = hv;
        sC[r][n] = base[(size_t)r * xcs + co + n];
    }
    if (tid < 64) scl[tid] = __expf(clb[(size_t)blk * 64 + tid]);
    float Dh = Dp[h];
    __syncthreads();
    int g1 = tid >> 4, g2 = tid & 15;
    int t0 = g1 * 4, p0 = g2 * 4;
    float m[4][4] = {};
    for (int n = 0; n < 64; n += 4){
        float4 cv[4], hv[4];
        #pragma unroll
        for (int i = 0; i < 4; i++) cv[i] = *(const float4*)&sC[t0 + i][n];
        #pragma unroll
        for (int j = 0; j < 4; j++) hv[j] = *(const float4*)&sH[p0 + j][n];
        #pragma unroll
        for (int i = 0; i < 4; i++)
            #pragma unroll
            for (int j = 0; j < 4; j++){
                m[i][j] = fmaf(cv[i].x, hv[j].x, m[i][j]);
                m[i][j] = fmaf(cv[i].y, hv[j].y, m[i][j]);
                m[i][j] = fmaf(cv[i].z, hv[j].z, m[i][j]);
                m[i][j] = fmaf(cv[i].w, hv[j].w, m[i][j]);
            }
    }
    #pragma unroll
    for (int i = 0; i < 4; i++){
        int t = t0 + i;
        size_t yi = (size_t)(b * L + l0 + t) * ys + h * 64 + p0;
        float4 yv = *(float4*)&y[yi];
        float4 xv = *(const float4*)&base[(size_t)t * xcs + h * 64 + p0];
        float e = scl[t];
        yv.x += e * m[i][0] + Dh * xv.x;
        yv.y += e * m[i][1] + Dh * xv.y;
        yv.z += e * m[i][2] + Dh * xv.z;
        yv.w += e * m[i][3] + Dh * xv.w;
        *(float4*)&y[yi] = yv;
    }
}

// ---------- center projection + q ----------
__global__ void k_center_q(const float* __restrict__ xs, const float* __restrict__ cw,
                           const float* __restrict__ cb, const float* __restrict__ qw,
                           const float* __restrict__ qb, float* __restrict__ q){
    __shared__ float xr[640];
    __shared__ float cen[128];
    int b = blockIdx.x, t = threadIdx.x; // 128 thr
    for (int idx = t; idx < 640; idx += 128)
        xr[idx] = xs[(size_t)b * 256 * 128 + idx];
    __syncthreads();
    float acc = cb[t];
    for (int c = 0; c < 128; c++){
        const float* wp = cw + (size_t)(t * 128 + c) * 5;
        #pragma unroll
        for (int l = 0; l < 5; l++) acc += xr[l * 128 + c] * wp[l];
    }
    cen[t] = acc;
    __syncthreads();
    float qa = qb[t];
    const float* wr = qw + (size_t)t * 128;
    for (int o = 0; o < 128; o++) qa += cen[o] * wr[o];
    q[b * 128 + t] = qa;
}

// ---------- attention softmax over l ----------
__global__ void k_attn(const float* __restrict__ q, const float* __restrict__ k,
                       float* __restrict__ attn){
    __shared__ float sm[16];
    __shared__ float qh[16];
    int blk = blockIdx.x; int b = blk >> 3, h = blk & 7; int l = threadIdx.x; // 256 thr
    if (l < 16) qh[l] = q[b * 128 + h * 16 + l];
    __syncthreads();
    const float* kp = k + ((size_t)(b * 256 + l)) * 128 + h * 16;
    float s = 0.f;
    #pragma unroll
    for (int d = 0; d < 16; d++) s += qh[d] * kp[d];
    s *= 0.25f;
    float mx = blk_max1(s, sm);
    float e = __expf(s - mx);
    float sum = blk_sum1(e, sm);
    attn[(size_t)blk * 256 + l] = e / sum;
}

// ---------- attention out, 8 l-rows per block ----------
__global__ __launch_bounds__(128) void k_attn_out(const float* __restrict__ v,
                                                  const float* __restrict__ attn,
                                                  const float* __restrict__ owt,
                                                  const float* __restrict__ ob,
                                                  float* __restrict__ xs){
    __shared__ float vp[8][128];
    int blk = blockIdx.x; int b = blk >> 5, l0 = (blk & 31) << 3;
    int t = threadIdx.x; // 128 thr
    int h = t >> 4;
    float a[8];
    #pragma unroll
    for (int r = 0; r < 8; r++)
        a[r] = attn[((size_t)(b * 8 + h)) * 256 + l0 + r];
    #pragma unroll
    for (int r = 0; r < 8; r++)
        vp[r][t] = v[((size_t)(b * 256 + l0 + r)) * 128 + t] * a[r];
    __syncthreads();
    float acc[8];
    float bv = ob[t];
    #pragma unroll
    for (int r = 0; r < 8; r++) acc[r] = bv;
    for (int j = 0; j < 128; j++){
        float w = owt[j * 128 + t];
        #pragma unroll
        for (int r = 0; r < 8; r++) acc[r] = fmaf(vp[r][j], w, acc[r]);
    }
    #pragma unroll
    for (int r = 0; r < 8; r++)
        xs[((size_t)(b * 256 + l0 + r)) * 128 + t] += acc[r];
}

// ---------- fused spectral attention: QK+softmax+AV+SO+residual+unsort ----------
__global__ __launch_bounds__(256) void k_spe_attn(const float* __restrict__ q2,
        const float* __restrict__ k2t, const float* __restrict__ v2,
        const float* __restrict__ sowt, const float* __restrict__ sob,
        const float* __restrict__ xs, const int* __restrict__ sidx,
        float* __restrict__ xr){
    __shared__ float qs[8][256];
    __shared__ float lgp[2][8][128];
    __shared__ float sa[8][132];
    __shared__ float av[8][256];
    __shared__ float mxs[8], sms[8];
    int blk = blockIdx.x; int b = blk >> 4; int i0 = (blk & 15) << 3;
    int t = threadIdx.x;
    for (int idx = t; idx < 2048; idx += 256){
        int ii = idx >> 8, d = idx & 255;
        qs[ii][d] = q2[((size_t)(b * 128 + i0 + ii)) * 256 + d];
    }
    __syncthreads();
    {
        int j = t & 127, dh = t >> 7;
        const float* kt = k2t + (size_t)b * 32768 + dh * 16384;
        float acc[8] = {};
        for (int dd = 0; dd < 128; dd++){
            float kv = kt[dd * 128 + j];
            int d = dh * 128 + dd;
            #pragma unroll
            for (int ii = 0; ii < 8; ii++) acc[ii] = fmaf(qs[ii][d], kv, acc[ii]);
        }
        #pragma unroll
        for (int ii = 0; ii < 8; ii++) lgp[dh][ii][j] = acc[ii];
    }
    __syncthreads();
    if (t < 128){
        #pragma unroll
        for (int ii = 0; ii < 8; ii++)
            sa[ii][t] = (lgp[0][ii][t] + lgp[1][ii][t]) * (1.f / 16.f);
    }
    __syncthreads();
    if (t < 8){
        float mx = -3.4e38f;
        for (int j = 0; j < 128; j++) mx = fmaxf(mx, sa[t][j]);
        float sm = 0.f;
        for (int j = 0; j < 128; j++) sm += __expf(sa[t][j] - mx);
        mxs[t] = mx; sms[t] = 1.f / sm;
    }
    __syncthreads();
    if (t < 128){
        #pragma unroll
        for (int ii = 0; ii < 8; ii++)
            sa[ii][t] = __expf(sa[ii][t] - mxs[ii]) * sms[ii];
    }
    __syncthreads();
    {
        float acc[8] = {};
        const float* vb = v2 + (size_t)b * 32768 + t;
        for (int j = 0; j < 128; j++){
            float vv = vb[(size_t)j * 256];
            #pragma unroll
            for (int ii = 0; ii < 8; ii++) acc[ii] = fmaf(sa[ii][j], vv, acc[ii]);
        }
        #pragma unroll
        for (int ii = 0; ii < 8; ii++) av[ii][t] = acc[ii];
    }
    __syncthreads();
    float acc[8] = {};
    for (int d = 0; d < 256; d++){
        float wv = sowt[d * 256 + t];
        #pragma unroll
        for (int ii = 0; ii < 8; ii++) acc[ii] = fmaf(av[ii][d], wv, acc[ii]);
    }
    float bias = sob[t];
    int p = sidx[b * 256 + t];
    const float* xin = xs + ((size_t)(b * 256 + t)) * 128 + i0;
    float* xout = xr + ((size_t)(b * 256 + p)) * 128 + i0;
    #pragma unroll
    for (int ii = 0; ii < 8; ii++) xout[ii] = xin[ii] + acc[ii] + bias;
}

// ---------- conv GEMM split-K=4 with fused im2col (pipelined, fp32) ----------
__global__ __launch_bounds__(256) void k_conv_gemm(const float* __restrict__ xr,
                                                   const float* __restrict__ W2,
                                                   float* __restrict__ part){
    __shared__ float As[16][68];
    __shared__ float Ws[16][64];
    int j0 = blockIdx.x * 64, r0 = blockIdx.y * 64, s = blockIdx.z;
    int tid = threadIdx.x;
    int cg = tid & 15, rg = tid >> 4;
    int arow = tid >> 2, akg = tid & 3;
    int wkk = tid >> 4, wseg = tid & 15;
    int r = r0 + arow; int b = r >> 6, oh = (r >> 3) & 7, ow = r & 7;
    float acc[4][4] = {};
    int kbeg = s * 288, kend = kbeg + 288;
    float4 a4, w4;
    {
        int k = kbeg + akg * 4;
        int khw = k >> 7, c = k & 127;
        int kh = khw / 3, kw = khw - kh * 3;
        int ih = oh * 2 - 1 + kh, iw = ow * 2 - 1 + kw;
        a4 = make_float4(0.f, 0.f, 0.f, 0.f);
        if (ih >= 0 && ih < 16 && iw >= 0 && iw < 16)
            a4 = *(const float4*)(xr + ((size_t)((b << 8) + (ih << 4) + iw)) * 128 + c);
        w4 = *(const float4*)(W2 + (size_t)(kbeg + wkk) * 128 + j0 + wseg * 4);
    }
    for (int k0 = kbeg; k0 < kend; k0 += 16){
        __syncthreads();
        As[akg * 4 + 0][arow] = a4.x; As[akg * 4 + 1][arow] = a4.y;
        As[akg * 4 + 2][arow] = a4.z; As[akg * 4 + 3][arow] = a4.w;
        Ws[wkk][wseg * 4 + 0] = w4.x; Ws[wkk][wseg * 4 + 1] = w4.y;
        Ws[wkk][wseg * 4 + 2] = w4.z; Ws[wkk][wseg * 4 + 3] = w4.w;
        __syncthreads();
        bool more = (k0 + 16 < kend);
        float4 na4, nw4;
        if (more){
            int k = k0 + 16 + akg * 4;
            int khw = k >> 7, c = k & 127;
            int kh = khw / 3, kw = khw - kh * 3;
            int ih = oh * 2 - 1 + kh, iw = ow * 2 - 1 + kw;
            na4 = make_float4(0.f, 0.f, 0.f, 0.f);
            if (ih >= 0 && ih < 16 && iw >= 0 && iw < 16)
                na4 = *(const float4*)(xr + ((size_t)((b << 8) + (ih << 4) + iw)) * 128 + c);
            nw4 = *(const float4*)(W2 + (size_t)(k0 + 16 + wkk) * 128 + j0 + wseg * 4);
        }
        #pragma unroll
        for (int kk = 0; kk < 16; kk++){
            float4 av4 = *(const float4*)(&As[kk][rg << 2]);
            float4 wv4 = *(const float4*)(&Ws[kk][cg << 2]);
            float av_[4] = {av4.x, av4.y, av4.z, av4.w};
            float wv_[4] = {wv4.x, wv4.y, wv4.z, wv4.w};
            #pragma unroll
            for (int ri = 0; ri < 4; ri++)
                #pragma unroll
                for (int ci = 0; ci < 4; ci++)
                    acc[ri][ci] = fmaf(av_[ri], wv_[ci], acc[ri][ci]);
        }
        if (more){ a4 = na4; w4 = nw4; }
    }
    float* pp = part + (size_t)s * 1024 * 128;
    #pragma unroll
    for (int ri = 0; ri < 4; ri++){
        int rr = r0 + (rg << 2) + ri;
        #pragma unroll
        for (int ci = 0; ci < 4; ci++){
            int j = j0 + (cg << 2) + ci;
            pp[(size_t)rr * 128 + j] = acc[ri][ci];
        }
    }
}

// ---------- reduce split-K partials + LayerNorm ----------
__global__ void k_part_ln(const float* __restrict__ part, const float* __restrict__ lnw,
                          const float* __restrict__ lnb, float* __restrict__ out){
    __shared__ float sm[16];
    int r = blockIdx.x, t = threadIdx.x; // 128 thr
    float v = part[(size_t)r * 128 + t]
            + part[(size_t)(1024 + r) * 128 + t]
            + part[(size_t)(2048 + r) * 128 + t]
            + part[(size_t)(3072 + r) * 128 + t];
    float a = v, q = v * v;
    blk_sum2(a, q, sm);
    float mu = a * (1.f / 128.f);
    float var = q * (1.f / 128.f) - mu * mu;
    float rs = rsqrtf(var + 1e-5f);
    out[(size_t)r * 128 + t] = (v - mu) * rs * lnw[t] + lnb[t];
}

extern "C" void kernel_launch(void* const* d_in, const int* in_sizes, int n_in,
                              void* d_out, int out_size, void* d_ws, size_t ws_size,
                              hipStream_t stream) {
    const float* x          = (const float*)d_in[0];
    const int*   sidx       = (const int*)  d_in[1];
    const float* spa_ln_w   = (const float*)d_in[2];
    const float* spa_ln_b   = (const float*)d_in[3];
    const float* spa_in_w   = (const float*)d_in[4];
    const float* spa_conv_w = (const float*)d_in[5];
    const float* spa_conv_b = (const float*)d_in[6];
    const float* spa_dt_bias= (const float*)d_in[7];
    const float* spa_A_log  = (const float*)d_in[8];
    const float* spa_D      = (const float*)d_in[9];
    const float* spa_rms_w  = (const float*)d_in[10];
    const float* spa_out_w  = (const float*)d_in[11];
    const float* spe_ln_w   = (const float*)d_in[12];
    const float* spe_ln_b   = (const float*)d_in[13];
    const float* spe_in_w   = (const float*)d_in[14];
    const float* spe_conv_w = (const float*)d_in[15];
    const float* spe_conv_b = (const float*)d_in[16];
    const float* spe_dt_bias= (const float*)d_in[17];
    const float* spe_A_log  = (const float*)d_in[18];
    const float* spe_D      = (const float*)d_in[19];
    const float* spe_rms_w  = (const float*)d_in[20];
    const float* spe_out_w  = (const float*)d_in[21];
    const float* norm_w     = (const float*)d_in[22];
    const float* norm_b     = (const float*)d_in[23];
    const float* cprj_w     = (const float*)d_in[24];
    const float* cprj_b     = (const float*)d_in[25];
    const float* aq_w       = (const float*)d_in[26];
    const float* aq_b       = (const float*)d_in[27];
    const float* ak_w       = (const float*)d_in[28];
    const float* ak_b       = (const float*)d_in[29];
    const float* av_w       = (const float*)d_in[30];
    const float* av_b       = (const float*)d_in[31];
    const float* ao_w       = (const float*)d_in[32];
    const float* ao_b       = (const float*)d_in[33];
    const float* sq_w       = (const float*)d_in[34];
    const float* sq_b       = (const float*)d_in[35];
    const float* sk_w       = (const float*)d_in[36];
    const float* sk_b       = (const float*)d_in[37];
    const float* sv_w       = (const float*)d_in[38];
    const float* sv_b       = (const float*)d_in[39];
    const float* so_w       = (const float*)d_in[40];
    const float* so_b       = (const float*)d_in[41];
    const float* ds_conv_w  = (const float*)d_in[42];
    const float* ds_ln_w    = (const float*)d_in[43];
    const float* ds_ln_b    = (const float*)d_in[44];

    float* ws = (float*)d_ws;
    // loop-live arena: 0 .. 7946240
    float* xs   = ws + 0;        // 524288
    float* zx   = ws + 1048576;  // -> 3686400
    float* xc   = ws + 3686400;  // -> 5259264
    float* dtb  = ws + 5259264;  // 32768
    float* dAb  = ws + 5292032;  // 32768 (log-dA)
    float* yb   = ws + 5324800;  // -> 6373376
    float* Sbuf = ws + 6373376;  // -> 7421952
    float* h1   = ws + 7421952;  // -> 7946240
    float* clbuf = ws + 524288;  // scratch (dead between uses)
    float* xT    = ws + 524288;  // scratch (dead after k_embed)
    // h1t aliases Sbuf: written by spatial gemm_gate (mode 4) AFTER chunk_y's
    // last S read, consumed by spectral gemm_ln BEFORE spectral ssd_chunk
    // rewrites Sbuf.
    float* h1t   = ws + 6373376;
    // weight transposes: PAST the loop-live arena
    float* owt   = ws + 7946240; // 16384 -> 7962624
    float* sowt  = ws + 7962624; // 65536 -> 8028160
    // attention-stage aliases (host regions dead post-loop)
    float* kb    = ws + 1048576;
    float* vb    = ws + 1572864;
    float* attnb = ws + 2097152;
    float* qb    = ws + 2129920;
    float* xt    = ws + 524288;
    float* q2    = ws + 3686400;
    float* k2t   = ws + 4210688;
    float* v2    = ws + 4734976;
    float* xr    = ws + 5586944; // -> 6111232
    float* part  = ws + 1048576; // kb/vb region, dead by conv_gemm

    k_tr_multi<<<592, 256, 0, stream>>>(x, xT, ao_w, owt, so_w, sowt);
    k_embed<<<4096, 128, 0, stream>>>(xT, sidx, xs);

    for (int i = 0; i < 2; i++){
        // ---- spatial mamba (L=256, nh=4, nc=4) ----
        k_gemm_ln<<<dim3(11, 64), 256, 0, stream>>>(xs, spa_in_w + (size_t)i * 644 * 128,
                                                    spa_ln_w + i * 128, spa_ln_b + i * 128,
                                                    zx, 644, 128);
        k_conv<<<4096, 256, 0, stream>>>(zx, spa_conv_w + (size_t)i * 384 * 4,
                                         spa_conv_b + i * 384, xc,
                                         spa_dt_bias + i * 4, spa_A_log + i * 4, dtb, dAb,
                                         256, 384, 644, 256, 4, 640);
        k_ssd_chunk<<<256, 256, 0, stream>>>(xc, dtb, dAb, yb, Sbuf, clbuf,
                                             256, 4, 4, 384, 256, 320, 256);
        k_chunk_y<<<256, 256, 0, stream>>>(xc, Sbuf, clbuf, spa_D + i * 4, yb,
                                           256, 4, 4, 384, 320, 256);
        k_gemm_gate<<<dim3(2, 128), 256, 0, stream>>>(yb, zx, spa_rms_w + i * 256,
                                                      spa_out_w + (size_t)i * 128 * 256,
                                                      xs, h1, h1t, 128, 256, 644, 4);
        // ---- spectral mamba (L=128, nh=8, nc=2) ----
        k_gemm_ln<<<dim3(19, 32), 256, 0, stream>>>(h1t, spe_in_w + (size_t)i * 1160 * 256,
                                                    spe_ln_w + i * 256, spe_ln_b + i * 256,
                                                    zx, 1160, 256);
        k_conv<<<2048, 256, 0, stream>>>(zx, spe_conv_w + (size_t)i * 640 * 4,
                                         spe_conv_b + i * 640, xc,
                                         spe_dt_bias + i * 8, spe_A_log + i * 8, dtb, dAb,
                                         128, 640, 1160, 512, 8, 1152);
        k_ssd_chunk<<<256, 256, 0, stream>>>(xc, dtb, dAb, yb, Sbuf, clbuf,
                                             128, 8, 2, 640, 512, 576, 512);
        k_chunk_y<<<256, 256, 0, stream>>>(xc, Sbuf, clbuf, spe_D + i * 8, yb,
                                           128, 8, 2, 640, 576, 512);
        k_gemm_gate<<<dim3(4, 64), 256, 0, stream>>>(yb, zx, spe_rms_w + i * 512,
                                                     spe_out_w + (size_t)i * 256 * 512,
                                                     h1, xs, nullptr, 256, 512, 1160, 2);
    }

    k_ln<<<4096, 128, 0, stream>>>(xs, norm_w, norm_b, xs, 128);
    k_center_q<<<16, 128, 0, stream>>>(xs, cprj_w, cprj_b, aq_w, aq_b, qb);
    {
        GJob jk = {ak_w, ak_b, kb, 0};
        GJob jv = {av_w, av_b, vb, 0};
        k_gemm3<<<dim3(2, 128, 2), 256, 0, stream>>>(xs, jk, jv, jk, 128, 128);
    }
    k_attn<<<128, 256, 0, stream>>>(qb, kb, attnb);
    k_attn_out<<<512, 128, 0, stream>>>(vb, attnb, owt, ao_b, xs);
    k_tr<<<dim3(4, 8, 16), 256, 0, stream>>>(xs, xt, 256, 128);
    {
        GJob jq = {sq_w, sq_b, q2, 0};
        GJob jk = {sk_w, sk_b, k2t, 3};
        GJob jv = {sv_w, sv_b, v2, 0};
        k_gemm3<<<dim3(4, 64, 3), 256, 0, stream>>>(xt, jq, jk, jv, 256, 256);
    }
    k_spe_attn<<<256, 256, 0, stream>>>(q2, k2t, v2, sowt, so_b, xs, sidx, xr);
    k_conv_gemm<<<dim3(2, 16, 4), 256, 0, stream>>>(xr, ds_conv_w, part);
    k_part_ln<<<1024, 128, 0, stream>>>(part, ds_ln_w, ds_ln_b, (float*)d_out);
}